// Round 15
// baseline (166.294 us; speedup 1.0000x reference)
//
#include <hip/hip_runtime.h>
#include <math.h>

#define NB   2
#define SQ   2048
#define SMEM 512
#define SKVN 2560
#define ND   1024
#define NH   16
#define DHN  64
#define NBH  32                     /* NB*NH */

typedef unsigned short u16;
typedef short bf16x8 __attribute__((ext_vector_type(8)));   // 8 bf16 = 4 VGPR
typedef float f32x4 __attribute__((ext_vector_type(4)));
typedef u16 u16x4 __attribute__((ext_vector_type(4)));
typedef u16 u16x8 __attribute__((ext_vector_type(8)));

#define CSC   0.1803368801111204f   /* 0.125 * log2(e) */

__device__ __forceinline__ u16 f2bf(float f) {             // RNE f32->bf16
    unsigned u = __float_as_uint(f);
    u += 0x7FFFu + ((u >> 16) & 1u);
    return (u16)(u >> 16);
}

__device__ __forceinline__ float bf2f(u16 v) {
    return __uint_as_float(((unsigned)v) << 16);
}

__device__ __forceinline__ void async16(u16* lds, const u16* g) {
    __builtin_amdgcn_global_load_lds(
        (const __attribute__((address_space(1))) void*)g,
        (__attribute__((address_space(3))) void*)lds, 16, 0, 0);
}

__device__ __forceinline__ unsigned lds_off(const void* p) {
    return (unsigned)(uintptr_t)(const __attribute__((address_space(3))) void*)p;
}

__device__ __forceinline__ u16x4 tr_read(unsigned a) {     // ds_read_b64_tr_b16
    u16x4 d;
    asm volatile("ds_read_b64_tr_b16 %0, %1" : "=v"(d) : "v"(a) : "memory");
    return d;
}

__device__ __forceinline__ unsigned cvtpk(float lo, float hi) {
    unsigned r;
    asm("v_cvt_pk_bf16_f32 %0, %1, %2" : "=v"(r) : "v"(lo), "v"(hi));
    return r;
}

__device__ __forceinline__ float exp2r(float x) {          // raw v_exp_f32
    float r;
    asm("v_exp_f32 %0, %1" : "=v"(r) : "v"(x));
    return r;
}

union PKU { unsigned u[2]; u16x4 v; };
union U8  { struct { u16x4 lo, hi; } p; bf16x8 v; };

// ---------------------------------------------------------------------------
// One launch: f32->bf16 for x, mems, Wq, Wk, Wv, Wo (+ mask -> bf16 log2-bias).
// ---------------------------------------------------------------------------
__global__ __launch_bounds__(256)
void cvt_all(const float* __restrict__ x, const float* __restrict__ mems,
             const float* __restrict__ W0, const float* __restrict__ W1,
             const float* __restrict__ W2, const float* __restrict__ W3,
             u16* __restrict__ xb, u16* __restrict__ memb,
             u16* __restrict__ d0, u16* __restrict__ d1,
             u16* __restrict__ d2, u16* __restrict__ d3,
             const int* __restrict__ mask, u16* __restrict__ mb16)
{
    const int bid = blockIdx.x;
    if (bid >= 4608) {                       // mask bias tail: 5120 elems
        const int i = (bid - 4608) * 256 + threadIdx.x;
        if (i < NB * SKVN)
            mb16[i] = mask[i] ? (u16)0 : f2bf(1.0e6f * CSC);
        return;
    }
    size_t i = ((size_t)bid * 256 + threadIdx.x) * 8;
    const float* s; u16* d;
    if (i < 4194304) { s = x; d = xb; }
    else if (i < 5242880) { s = mems; d = memb; i -= 4194304; }
    else {
        size_t off = i - 5242880;
        const int wi = (int)(off >> 20);
        i = off & 1048575;
        switch (wi) {
            case 0:  s = W0; d = d0; break;
            case 1:  s = W1; d = d1; break;
            case 2:  s = W2; d = d2; break;
            default: s = W3; d = d3; break;
        }
    }
    float4 a = *(const float4*)(s + i);
    float4 b = *(const float4*)(s + i + 4);
    u16x8 o;
    o[0]=f2bf(a.x); o[1]=f2bf(a.y); o[2]=f2bf(a.z); o[3]=f2bf(a.w);
    o[4]=f2bf(b.x); o[5]=f2bf(b.y); o[6]=f2bf(b.z); o[7]=f2bf(b.w);
    *(u16x8*)(d + i) = o;
}

// A-row pointer with fused [mems; x] concat (NB=2 hardcoded)
__device__ __forceinline__ const u16* arow_ptr(const u16* x, const u16* mems,
                                               int grow, int T, int memLen) {
    int b = grow >= T ? 1 : 0;
    int t = grow - b * T;
    if (memLen > 0 && t < memLen)
        return mems + ((size_t)(b * memLen + t)) * ND;
    return x + ((size_t)(b * (T - memLen) + (t - memLen))) * ND;
}

// ---------------------------------------------------------------------------
// bf16 GEMM body (R6 form, verified) — used by gemm_qkv.
// ---------------------------------------------------------------------------
__device__ __forceinline__
void gemm_body(const u16* __restrict__ x, const u16* __restrict__ mems,
               const u16* __restrict__ W, const float* __restrict__ bias,
               void* __restrict__ out, int T, int memLen, int mode,
               int bx, int by, u16* As0, u16* As1, u16* Bs0, u16* Bs1)
{
    u16* As[2] = {As0, As1};
    u16* Bs[2] = {Bs0, Bs1};

    const int tid  = threadIdx.x;
    const int wave = tid >> 6, lane = tid & 63;
    const int lg = lane >> 4, li = lane & 15;
    const int wr = (wave >> 1) * 64, wc = (wave & 1) * 64;
    const int row0 = bx * 128, col0 = by * 128;

    const int srow = lane >> 2;
    const int sslot = lane & 3;

    f32x4 acc[4][4];
    const f32x4 zf = {0.f, 0.f, 0.f, 0.f};
#pragma unroll
    for (int m = 0; m < 4; ++m)
#pragma unroll
        for (int n = 0; n < 4; ++n) acc[m][n] = zf;

    auto stage = [&](int c, int kt) {
        const int k0 = kt * 32;
#pragma unroll
        for (int ch = wave; ch < 8; ch += 4) {
            const int r = ch * 16 + srow;
            const int gs = sslot ^ ((r ^ (r >> 2)) & 3);
            async16(&As[c][ch * 512],
                    arow_ptr(x, mems, row0 + r, T, memLen) + k0 + gs * 8);
        }
#pragma unroll
        for (int ch = wave; ch < 8; ch += 4) {
            const int r = ch * 16 + srow;
            const int gs = sslot ^ ((r ^ (r >> 2)) & 3);
            async16(&Bs[c][ch * 512],
                    W + (size_t)(col0 + r) * ND + k0 + gs * 8);
        }
    };

    stage(0, 0);
    int cur = 0;
    for (int kt = 0; kt < 32; ++kt) {
        __syncthreads();
        if (kt + 1 < 32) stage(cur ^ 1, kt + 1);

        bf16x8 af[4], bfr[4];
#pragma unroll
        for (int m = 0; m < 4; ++m) {
            const int r = wr + m * 16 + li;
            af[m] = *(const bf16x8*)&As[cur][r * 32 + ((lg ^ ((r ^ (r >> 2)) & 3)) << 3)];
        }
#pragma unroll
        for (int n = 0; n < 4; ++n) {
            const int r = wc + n * 16 + li;
            bfr[n] = *(const bf16x8*)&Bs[cur][r * 32 + ((lg ^ ((r ^ (r >> 2)) & 3)) << 3)];
        }
#pragma unroll
        for (int m = 0; m < 4; ++m)
#pragma unroll
            for (int n = 0; n < 4; ++n)
                acc[m][n] = __builtin_amdgcn_mfma_f32_16x16x32_bf16(
                                af[m], bfr[n], acc[m][n], 0, 0, 0);
        cur ^= 1;
    }

#pragma unroll
    for (int n = 0; n < 4; ++n) {
        const int col = col0 + wc + n * 16 + li;
        const float bv = bias[col];
#pragma unroll
        for (int m = 0; m < 4; ++m) {
            const int rbase = row0 + wr + m * 16 + 4 * lg;
            if (mode == 1) {
                u16* o = (u16*)out;
                const int h = col >> 6, dh = col & 63;
#pragma unroll
                for (int r = 0; r < 4; ++r) {
                    const int grow = rbase + r;
                    const int b = grow >= T ? 1 : 0;
                    const int t = grow - b * T;
                    o[(((size_t)b * NH + h) * T + t) * DHN + dh] =
                        f2bf(acc[m][n][r] + bv);
                }
            } else {
                u16* o = (u16*)out;
                const int h = col >> 6, dh = col & 63;
                const int b = rbase >= T ? 1 : 0;
                const int t = rbase - b * T;
                u16x4 pk;
                pk[0] = f2bf(acc[m][n][0] + bv);
                pk[1] = f2bf(acc[m][n][1] + bv);
                pk[2] = f2bf(acc[m][n][2] + bv);
                pk[3] = f2bf(acc[m][n][3] + bv);
                *(u16x4*)&o[(((size_t)b * NH + h) * DHN + dh) * (size_t)T + t] = pk;
            }
        }
    }
}

// Merged Q+K+V projections: 896 wg, XCD-bijective swizzle, id-decoded.
__global__ __launch_bounds__(256)
void gemm_qkv(const u16* __restrict__ xb, const u16* __restrict__ memb,
              const u16* __restrict__ Wq, const float* __restrict__ bq, u16* Qb,
              const u16* __restrict__ Wk, const float* __restrict__ bk, u16* Kb,
              const u16* __restrict__ Wv, const float* __restrict__ bv, u16* Vtb)
{
    __shared__ u16 As[2][128 * 32];
    __shared__ u16 Bs[2][128 * 32];
    const int id = (blockIdx.x & 7) * 112 + (blockIdx.x >> 3);  // 896 = 8*112
    if (id < 256) {
        gemm_body(xb, nullptr, Wq, bq, Qb, SQ, 0, 1, id & 31, id >> 5,
                  As[0], As[1], Bs[0], Bs[1]);
    } else if (id < 576) {
        const int t = id - 256;
        gemm_body(xb, memb, Wk, bk, Kb, SKVN, SMEM, 1, t % 40, t / 40,
                  As[0], As[1], Bs[0], Bs[1]);
    } else {
        const int t = id - 576;
        gemm_body(xb, memb, Wv, bv, Vtb, SKVN, SMEM, 2, t % 40, t / 40,
                  As[0], As[1], Bs[0], Bs[1]);
    }
}

// ---------------------------------------------------------------------------
// O-projection: 64x128 tiles -> 512 wgs (R11, verified).
// ---------------------------------------------------------------------------
__global__ __launch_bounds__(256)
void gemm_o(const u16* __restrict__ x, const u16* __restrict__ W,
            const float* __restrict__ bias, float* __restrict__ out)
{
    __shared__ u16 As[2][64 * 32];
    __shared__ u16 Bs[2][128 * 32];

    const int tid  = threadIdx.x;
    const int wave = tid >> 6, lane = tid & 63;
    const int lg = lane >> 4, li = lane & 15;
    const int wr = (wave >> 1) * 32, wc = (wave & 1) * 64;

    const int id = (blockIdx.x & 7) * 64 + (blockIdx.x >> 3);   // 512 = 8*64
    const int row0 = (id >> 3) * 64, col0 = (id & 7) * 128;

    const int srow = lane >> 2;
    const int sslot = lane & 3;

    f32x4 acc[2][4];
    const f32x4 zf = {0.f, 0.f, 0.f, 0.f};
#pragma unroll
    for (int m = 0; m < 2; ++m)
#pragma unroll
        for (int n = 0; n < 4; ++n) acc[m][n] = zf;

    auto stage = [&](int c, int kt) {
        const int k0 = kt * 32;
        {   // A: 4 chunks of 16 rows; one per wave
            const int r = wave * 16 + srow;
            const int gs = sslot ^ ((r ^ (r >> 2)) & 3);
            async16(&As[c][wave * 512],
                    x + (size_t)(row0 + r) * ND + k0 + gs * 8);
        }
#pragma unroll
        for (int ch = wave; ch < 8; ch += 4) {   // B: 8 chunks; two per wave
            const int r = ch * 16 + srow;
            const int gs = sslot ^ ((r ^ (r >> 2)) & 3);
            async16(&Bs[c][ch * 512],
                    W + (size_t)(col0 + r) * ND + k0 + gs * 8);
        }
    };

    stage(0, 0);
    int cur = 0;
    for (int kt = 0; kt < 32; ++kt) {
        __syncthreads();
        if (kt + 1 < 32) stage(cur ^ 1, kt + 1);

        bf16x8 af[2], bfr[4];
#pragma unroll
        for (int m = 0; m < 2; ++m) {
            const int r = wr + m * 16 + li;
            af[m] = *(const bf16x8*)&As[cur][r * 32 + ((lg ^ ((r ^ (r >> 2)) & 3)) << 3)];
        }
#pragma unroll
        for (int n = 0; n < 4; ++n) {
            const int r = wc + n * 16 + li;
            bfr[n] = *(const bf16x8*)&Bs[cur][r * 32 + ((lg ^ ((r ^ (r >> 2)) & 3)) << 3)];
        }
#pragma unroll
        for (int m = 0; m < 2; ++m)
#pragma unroll
            for (int n = 0; n < 4; ++n)
                acc[m][n] = __builtin_amdgcn_mfma_f32_16x16x32_bf16(
                                af[m], bfr[n], acc[m][n], 0, 0, 0);
        cur ^= 1;
    }

#pragma unroll
    for (int n = 0; n < 4; ++n) {
        const int col = col0 + wc + n * 16 + li;
        const float bv = bias[col];
#pragma unroll
        for (int m = 0; m < 2; ++m) {
            const int rbase = row0 + wr + m * 16 + 4 * lg;
#pragma unroll
            for (int r = 0; r < 4; ++r)
                out[(size_t)(rbase + r) * ND + col] = acc[m][n][r] + bv;
        }
    }
}

// ---------------------------------------------------------------------------
// MFMA flash attention v11: 8 waves / Q-tile 256 (R14 geometry + ledger)
// with the two q-halves SOFTWARE-PIPELINED within each tile:
//   QK_A -> QK_B -> pack_A (under QK_B) -> trA -> PV_A -> pack_B (under PV_A)
//   -> trB -> PV_B.  K frags hoisted to regs (read once, shared by halves).
// ---------------------------------------------------------------------------
__global__ __launch_bounds__(512)
void attn_mfma(const u16* __restrict__ Qw, const u16* __restrict__ Kw,
               const u16* __restrict__ Vt, const u16* __restrict__ mb16,
               u16* __restrict__ AO)
{
    __shared__ u16 Ks[2][64 * 64];
    __shared__ u16 Vs[2][64 * 64];
    __shared__ u16 Ps[8][2048];          // per-wave: 2 P^T tiles [64 kv][16 q]
    __shared__ u16 Ms[SKVN];             // bf16 mask bias row (5 KB)

    const int tid  = threadIdx.x;
    const int wave = tid >> 6, lane = tid & 63;
    const int lg = lane >> 4, li = lane & 15;

    const int wg = blockIdx.x;                   // 256 wgs
    const int sw = (wg & 7) * 32 + (wg >> 3);    // XCD-contiguous chunks
    const int bh = sw >> 3;                      // 8 q-tiles per bh
    const int q0 = (sw & 7) * 256;
    const int b = bh >> 4, h = bh & 15;

    const u16* Kg = Kw + (size_t)bh * SKVN * DHN;
    const u16* Vg = Vt + (size_t)bh * DHN * SKVN;
    const u16* m16row = mb16 + (size_t)b * SKVN;

    // Q fragments: rows q0 + wave*32 + li (half A) and +16 (half B)
    bf16x8 qA0, qA1, qB0, qB1;
    {
        const u16* Qp = Qw + ((size_t)bh * SQ + q0 + wave * 32 + li) * DHN;
        qA0 = *(const bf16x8*)(Qp + lg * 8);
        qA1 = *(const bf16x8*)(Qp + 32 + lg * 8);
        qB0 = *(const bf16x8*)(Qp + 16 * DHN + lg * 8);
        qB1 = *(const bf16x8*)(Qp + 16 * DHN + 32 + lg * 8);
    }

    // stage mask-bias row into LDS (one-time; fully drained by syncthreads)
    for (int i = tid * 8; i < SKVN; i += 4096)
        *(u16x8*)&Ms[i] = *(const u16x8*)(m16row + i);

    U8 ou;
#pragma unroll
    for (int i = 0; i < 4; ++i) { ou.p.lo[i] = 0x3F80; ou.p.hi[i] = 0x3F80; }
    const bf16x8 onesb = ou.v;

    const int srow = lane >> 3, sslot = lane & 7;

    auto stage = [&](int c, int t) {             // exactly 2 vmem ops per wave
        const int kv0 = t * 64;
        const int r = wave * 8 + srow;           // 8 waves cover 8 chunks
        async16(&Ks[c][wave * 512],
                Kg + (size_t)(kv0 + r) * DHN + ((sslot ^ (r & 7)) << 3));
        async16(&Vs[c][wave * 512],
                Vg + (size_t)r * SKVN + kv0 + ((sslot ^ (r & 7)) << 3));
    };

    f32x4 oA[4], oB[4], laccA, laccB;
    const f32x4 zf = {0.f, 0.f, 0.f, 0.f};
#pragma unroll
    for (int n = 0; n < 4; ++n) { oA[n] = zf; oB[n] = zf; }
    laccA = zf; laccB = zf;

    u16* Pw = &Ps[wave][0];
    const unsigned paA = lds_off(Pw) + 256u * lg + 8u * li;
    const unsigned paB = paA + 2048u;            // half-B P^T tile

    // Drain EVERYTHING (Q loads, mask staging) so the ledger starts clean.
    __syncthreads();
    __builtin_amdgcn_sched_barrier(0);
    stage(0, 0);                                 // S0: 2 ops
    __builtin_amdgcn_sched_barrier(0);
    stage(1, 1);                                 // S1: 2 ops
    __builtin_amdgcn_sched_barrier(0);

    const int NT = SKVN / 64;
    int cur = 0;
    for (int t = 0; t < NT; ++t) {
        // Drain stage(t): outstanding = [S(t)(2), S(t+1)(2)] -> vmcnt(2).
        // Last iteration has no S(t+1) in flight -> full drain.
        if (t == NT - 1) asm volatile("s_waitcnt vmcnt(0)" ::: "memory");
        else             asm volatile("s_waitcnt vmcnt(2)" ::: "memory");
        __builtin_amdgcn_s_barrier();
        __builtin_amdgcn_sched_barrier(0);

        // mask bias for this tile from LDS (broadcast reads)
        float mbc[4];
#pragma unroll
        for (int n = 0; n < 4; ++n)
            mbc[n] = bf2f(Ms[t * 64 + n * 16 + li]);

        // ---- K frags read once, kept in regs (shared by both halves) ----
        bf16x8 kb0[4], kb1[4];
#pragma unroll
        for (int n = 0; n < 4; ++n) {
            const int r = n * 16 + li;
            kb0[n] = *(const bf16x8*)&Ks[cur][r * 64 + ((lg ^ (r & 7)) << 3)];
            kb1[n] = *(const bf16x8*)&Ks[cur][r * 64 + (((4 + lg) ^ (r & 7)) << 3)];
        }

        // ---- QK: half A first (its results ready early), then half B ----
        __builtin_amdgcn_s_setprio(1);
        f32x4 sA[4], sB[4];
#pragma unroll
        for (int n = 0; n < 4; ++n) {
            f32x4 z = zf;
            z     = __builtin_amdgcn_mfma_f32_16x16x32_bf16(qA0, kb0[n], z, 0, 0, 0);
            sA[n] = __builtin_amdgcn_mfma_f32_16x16x32_bf16(qA1, kb1[n], z, 0, 0, 0);
        }
#pragma unroll
        for (int n = 0; n < 4; ++n) {
            f32x4 y = zf;
            y     = __builtin_amdgcn_mfma_f32_16x16x32_bf16(qB0, kb0[n], y, 0, 0, 0);
            sB[n] = __builtin_amdgcn_mfma_f32_16x16x32_bf16(qB1, kb1[n], y, 0, 0, 0);
        }
        __builtin_amdgcn_s_setprio(0);

        // ---- pack A (VALU; overlaps QK_B MFMA execution) ----
#pragma unroll
        for (int n = 0; n < 4; ++n) {
            const float mb = mbc[n];
            const int pw = (n * 16 + li) * 16 + lg * 4;
            PKU ua;
            ua.u[0] = cvtpk(exp2r(fmaf(sA[n][0], CSC, -mb)),
                            exp2r(fmaf(sA[n][1], CSC, -mb)));
            ua.u[1] = cvtpk(exp2r(fmaf(sA[n][2], CSC, -mb)),
                            exp2r(fmaf(sA[n][3], CSC, -mb)));
            *(u16x4*)&Pw[pw] = ua.v;
        }

        // ---- tr_read A ----
        u16x4 a00 = tr_read(paA);
        u16x4 a01 = tr_read(paA + 128);
        u16x4 a10 = tr_read(paA + 1024);
        u16x4 a11 = tr_read(paA + 1024 + 128);
        asm volatile("s_waitcnt lgkmcnt(0)" ::: "memory");
        __builtin_amdgcn_sched_barrier(0);
        U8 pA0, pA1;
        pA0.p.lo = a00; pA0.p.hi = a01;
        pA1.p.lo = a10; pA1.p.hi = a11;

        // ---- PV_A (MFMA) — pack_B below issues while these execute ----
        __builtin_amdgcn_s_setprio(1);
        laccA = __builtin_amdgcn_mfma_f32_16x16x32_bf16(pA0.v, onesb, laccA, 0, 0, 0);
        laccA = __builtin_amdgcn_mfma_f32_16x16x32_bf16(pA1.v, onesb, laccA, 0, 0, 0);
#pragma unroll
        for (int n = 0; n < 4; ++n) {
            const int r = n * 16 + li;
            bf16x8 vb0 = *(const bf16x8*)&Vs[cur][r * 64 + ((lg ^ (r & 7)) << 3)];
            bf16x8 vb1 = *(const bf16x8*)&Vs[cur][r * 64 + (((4 + lg) ^ (r & 7)) << 3)];
            oA[n] = __builtin_amdgcn_mfma_f32_16x16x32_bf16(pA0.v, vb0, oA[n], 0, 0, 0);
            oA[n] = __builtin_amdgcn_mfma_f32_16x16x32_bf16(pA1.v, vb1, oA[n], 0, 0, 0);
        }
        __builtin_amdgcn_s_setprio(0);

        // ---- pack B (VALU; overlaps PV_A MFMA execution) ----
#pragma unroll
        for (int n = 0; n < 4; ++n) {
            const float mb = mbc[n];
            const int pw = (n * 16 + li) * 16 + lg * 4;
            PKU ub;
            ub.u[0] = cvtpk(exp2r(fmaf(sB[n][0], CSC, -mb)),
                            exp2r(fmaf(sB[n][1], CSC, -mb)));
            ub.u[1] = cvtpk(exp2r(fmaf(sB[n][2], CSC, -mb)),
                            exp2r(fmaf(sB[n][3], CSC, -mb)));
            *(u16x4*)&Pw[1024 + pw] = ub.v;
        }

        // ---- tr_read B ----
        u16x4 b00 = tr_read(paB);
        u16x4 b01 = tr_read(paB + 128);
        u16x4 b10 = tr_read(paB + 1024);
        u16x4 b11 = tr_read(paB + 1024 + 128);
        asm volatile("s_waitcnt lgkmcnt(0)" ::: "memory");
        __builtin_amdgcn_sched_barrier(0);
        U8 pB0, pB1;
        pB0.p.lo = b00; pB0.p.hi = b01;
        pB1.p.lo = b10; pB1.p.hi = b11;

        // ---- PV_B (MFMA) ----
        __builtin_amdgcn_s_setprio(1);
        laccB = __builtin_amdgcn_mfma_f32_16x16x32_bf16(pB0.v, onesb, laccB, 0, 0, 0);
        laccB = __builtin_amdgcn_mfma_f32_16x16x32_bf16(pB1.v, onesb, laccB, 0, 0, 0);
#pragma unroll
        for (int n = 0; n < 4; ++n) {
            const int r = n * 16 + li;
            bf16x8 vb0 = *(const bf16x8*)&Vs[cur][r * 64 + ((lg ^ (r & 7)) << 3)];
            bf16x8 vb1 = *(const bf16x8*)&Vs[cur][r * 64 + (((4 + lg) ^ (r & 7)) << 3)];
            oB[n] = __builtin_amdgcn_mfma_f32_16x16x32_bf16(pB0.v, vb0, oB[n], 0, 0, 0);
            oB[n] = __builtin_amdgcn_mfma_f32_16x16x32_bf16(pB1.v, vb1, oB[n], 0, 0, 0);
        }
        __builtin_amdgcn_s_setprio(0);

        // all own LDS reads of buf[cur] complete -> free the buffer
        asm volatile("s_waitcnt lgkmcnt(0)" ::: "memory");
        __builtin_amdgcn_s_barrier();
        __builtin_amdgcn_sched_barrier(0);

        if (t + 2 < NT) stage(cur, t + 2);       // S(t+2): 2 ops into freed buf
        cur ^= 1;
    }

    // epilogue: AO[b, q, h*64+d] bf16 — halves A and B
#pragma unroll
    for (int r = 0; r < 4; ++r) {
        const float invA = 1.f / laccA[r];
        const float invB = 1.f / laccB[r];
        const int rowA = q0 + wave * 32 + 4 * lg + r;
#pragma unroll
        for (int n = 0; n < 4; ++n) {
            const int col = h * DHN + n * 16 + li;
            AO[((size_t)b * SQ + rowA) * ND + col] = f2bf(oA[n][r] * invA);
            AO[((size_t)b * SQ + rowA + 16) * ND + col] = f2bf(oB[n][r] * invB);
        }
    }
}

// ---------------------------------------------------------------------------
extern "C" void kernel_launch(void* const* d_in, const int* in_sizes, int n_in,
                              void* d_out, int out_size, void* d_ws, size_t ws_size,
                              hipStream_t stream)
{
    const float* x    = (const float*)d_in[0];
    const float* mems = (const float*)d_in[1];
    const int*   mask = (const int*)d_in[3];
    const float* Wq = (const float*)d_in[4];  const float* bq = (const float*)d_in[5];
    const float* Wk = (const float*)d_in[6];  const float* bk = (const float*)d_in[7];
    const float* Wv = (const float*)d_in[8];  const float* bv = (const float*)d_in[9];
    const float* Wo = (const float*)d_in[10]; const float* bo = (const float*)d_in[11];
    float* out = (float*)d_out;

    u16* ws = (u16*)d_ws;
    u16* xb   = ws;
    u16* memb = xb   + (size_t)NB * SQ * ND;
    u16* Wqb  = memb + (size_t)NB * SMEM * ND;
    u16* Wkb  = Wqb + (size_t)ND * ND;
    u16* Wvb  = Wkb + (size_t)ND * ND;
    u16* Wob  = Wvb + (size_t)ND * ND;
    u16* Qb   = Wob + (size_t)ND * ND;
    u16* Kb   = Qb  + (size_t)NB * NH * SQ * DHN;
    u16* Vtb  = Kb  + (size_t)NB * NH * SKVN * DHN;
    u16* AOb  = Vtb + (size_t)NB * NH * SKVN * DHN;
    u16* mb16 = AOb + (size_t)NB * SQ * ND;

    const dim3 blk(256);
    cvt_all<<<dim3(4628), blk, 0, stream>>>(x, mems, Wq, Wk, Wv, Wo,
                                            xb, memb, Wqb, Wkb, Wvb, Wob,
                                            mask, mb16);
    gemm_qkv<<<dim3(896), blk, 0, stream>>>(xb, memb,
                                            Wqb, bq, Qb,
                                            Wkb, bk, Kb,
                                            Wvb, bv, Vtb);
    attn_mfma<<<dim3(256), dim3(512), 0, stream>>>(Qb, Kb, Vtb, mb16, AOb);
    gemm_o<<<dim3(512), blk, 0, stream>>>(AOb, Wob, bo, out);
}

// Round 16
// 162.295 us; speedup vs baseline: 1.0246x; 1.0246x over previous
//
#include <hip/hip_runtime.h>
#include <math.h>

#define NB   2
#define SQ   2048
#define SMEM 512
#define SKVN 2560
#define ND   1024
#define NH   16
#define DHN  64
#define NBH  32                     /* NB*NH */

typedef unsigned short u16;
typedef short bf16x8 __attribute__((ext_vector_type(8)));   // 8 bf16 = 4 VGPR
typedef float f32x4 __attribute__((ext_vector_type(4)));
typedef u16 u16x4 __attribute__((ext_vector_type(4)));
typedef u16 u16x8 __attribute__((ext_vector_type(8)));

#define CSC   0.1803368801111204f   /* 0.125 * log2(e) */

__device__ __forceinline__ u16 f2bf(float f) {             // RNE f32->bf16
    unsigned u = __float_as_uint(f);
    u += 0x7FFFu + ((u >> 16) & 1u);
    return (u16)(u >> 16);
}

__device__ __forceinline__ float bf2f(u16 v) {
    return __uint_as_float(((unsigned)v) << 16);
}

__device__ __forceinline__ void async16(u16* lds, const u16* g) {
    __builtin_amdgcn_global_load_lds(
        (const __attribute__((address_space(1))) void*)g,
        (__attribute__((address_space(3))) void*)lds, 16, 0, 0);
}

__device__ __forceinline__ unsigned lds_off(const void* p) {
    return (unsigned)(uintptr_t)(const __attribute__((address_space(3))) void*)p;
}

__device__ __forceinline__ u16x4 tr_read(unsigned a) {     // ds_read_b64_tr_b16
    u16x4 d;
    asm volatile("ds_read_b64_tr_b16 %0, %1" : "=v"(d) : "v"(a) : "memory");
    return d;
}

__device__ __forceinline__ unsigned cvtpk(float lo, float hi) {
    unsigned r;
    asm("v_cvt_pk_bf16_f32 %0, %1, %2" : "=v"(r) : "v"(lo), "v"(hi));
    return r;
}

__device__ __forceinline__ float exp2r(float x) {          // raw v_exp_f32
    float r;
    asm("v_exp_f32 %0, %1" : "=v"(r) : "v"(x));
    return r;
}

union PKU { unsigned u[2]; u16x4 v; };
union U8  { struct { u16x4 lo, hi; } p; bf16x8 v; };

// ---------------------------------------------------------------------------
// One launch: f32->bf16 for x, mems, Wq, Wk, Wv, Wo (+ mask -> bf16 log2-bias).
// ---------------------------------------------------------------------------
__global__ __launch_bounds__(256)
void cvt_all(const float* __restrict__ x, const float* __restrict__ mems,
             const float* __restrict__ W0, const float* __restrict__ W1,
             const float* __restrict__ W2, const float* __restrict__ W3,
             u16* __restrict__ xb, u16* __restrict__ memb,
             u16* __restrict__ d0, u16* __restrict__ d1,
             u16* __restrict__ d2, u16* __restrict__ d3,
             const int* __restrict__ mask, u16* __restrict__ mb16)
{
    const int bid = blockIdx.x;
    if (bid >= 4608) {                       // mask bias tail: 5120 elems
        const int i = (bid - 4608) * 256 + threadIdx.x;
        if (i < NB * SKVN)
            mb16[i] = mask[i] ? (u16)0 : f2bf(1.0e6f * CSC);
        return;
    }
    size_t i = ((size_t)bid * 256 + threadIdx.x) * 8;
    const float* s; u16* d;
    if (i < 4194304) { s = x; d = xb; }
    else if (i < 5242880) { s = mems; d = memb; i -= 4194304; }
    else {
        size_t off = i - 5242880;
        const int wi = (int)(off >> 20);
        i = off & 1048575;
        switch (wi) {
            case 0:  s = W0; d = d0; break;
            case 1:  s = W1; d = d1; break;
            case 2:  s = W2; d = d2; break;
            default: s = W3; d = d3; break;
        }
    }
    float4 a = *(const float4*)(s + i);
    float4 b = *(const float4*)(s + i + 4);
    u16x8 o;
    o[0]=f2bf(a.x); o[1]=f2bf(a.y); o[2]=f2bf(a.z); o[3]=f2bf(a.w);
    o[4]=f2bf(b.x); o[5]=f2bf(b.y); o[6]=f2bf(b.z); o[7]=f2bf(b.w);
    *(u16x8*)(d + i) = o;
}

// A-row pointer with fused [mems; x] concat (NB=2 hardcoded)
__device__ __forceinline__ const u16* arow_ptr(const u16* x, const u16* mems,
                                               int grow, int T, int memLen) {
    int b = grow >= T ? 1 : 0;
    int t = grow - b * T;
    if (memLen > 0 && t < memLen)
        return mems + ((size_t)(b * memLen + t)) * ND;
    return x + ((size_t)(b * (T - memLen) + (t - memLen))) * ND;
}

// ---------------------------------------------------------------------------
// bf16 GEMM body (R6 layout + R13-style counted-vmcnt 2-barrier pipeline):
// stage() = exactly 4 vmem ops/wave; in-loop first barrier waits vmcnt(4)
// (S(t) drained, S(t+1) in flight), last iteration peeled to vmcnt(0);
// stage(t+2) issued after the read-done barrier into the freed buffer.
// ---------------------------------------------------------------------------
__device__ __forceinline__
void gemm_body(const u16* __restrict__ x, const u16* __restrict__ mems,
               const u16* __restrict__ W, const float* __restrict__ bias,
               void* __restrict__ out, int T, int memLen, int mode,
               int bx, int by, u16* As0, u16* As1, u16* Bs0, u16* Bs1)
{
    u16* As[2] = {As0, As1};
    u16* Bs[2] = {Bs0, Bs1};

    const int tid  = threadIdx.x;
    const int wave = tid >> 6, lane = tid & 63;
    const int lg = lane >> 4, li = lane & 15;
    const int wr = (wave >> 1) * 64, wc = (wave & 1) * 64;
    const int row0 = bx * 128, col0 = by * 128;

    const int srow = lane >> 2;
    const int sslot = lane & 3;

    f32x4 acc[4][4];
    const f32x4 zf = {0.f, 0.f, 0.f, 0.f};
#pragma unroll
    for (int m = 0; m < 4; ++m)
#pragma unroll
        for (int n = 0; n < 4; ++n) acc[m][n] = zf;

    auto stage = [&](int c, int kt) {            // exactly 4 vmem ops per wave
        const int k0 = kt * 32;
#pragma unroll
        for (int ch = wave; ch < 8; ch += 4) {
            const int r = ch * 16 + srow;
            const int gs = sslot ^ ((r ^ (r >> 2)) & 3);
            async16(&As[c][ch * 512],
                    arow_ptr(x, mems, row0 + r, T, memLen) + k0 + gs * 8);
        }
#pragma unroll
        for (int ch = wave; ch < 8; ch += 4) {
            const int r = ch * 16 + srow;
            const int gs = sslot ^ ((r ^ (r >> 2)) & 3);
            async16(&Bs[c][ch * 512],
                    W + (size_t)(col0 + r) * ND + k0 + gs * 8);
        }
    };

    // prologue: pinned issue order, ledger = S0(4), S1(4)
    stage(0, 0);
    __builtin_amdgcn_sched_barrier(0);
    stage(1, 1);
    __builtin_amdgcn_sched_barrier(0);

    int cur = 0;
    for (int kt = 0; kt < 32; ++kt) {
        // drain S(kt): outstanding = [S(kt)(4), S(kt+1)(4)] -> vmcnt(4);
        // last iteration has no S(kt+1) in flight -> full drain.
        if (kt == 31) asm volatile("s_waitcnt vmcnt(0)" ::: "memory");
        else          asm volatile("s_waitcnt vmcnt(4)" ::: "memory");
        __builtin_amdgcn_s_barrier();
        __builtin_amdgcn_sched_barrier(0);

        bf16x8 af[4], bfr[4];
#pragma unroll
        for (int m = 0; m < 4; ++m) {
            const int r = wr + m * 16 + li;
            af[m] = *(const bf16x8*)&As[cur][r * 32 + ((lg ^ ((r ^ (r >> 2)) & 3)) << 3)];
        }
#pragma unroll
        for (int n = 0; n < 4; ++n) {
            const int r = wc + n * 16 + li;
            bfr[n] = *(const bf16x8*)&Bs[cur][r * 32 + ((lg ^ ((r ^ (r >> 2)) & 3)) << 3)];
        }
#pragma unroll
        for (int m = 0; m < 4; ++m)
#pragma unroll
            for (int n = 0; n < 4; ++n)
                acc[m][n] = __builtin_amdgcn_mfma_f32_16x16x32_bf16(
                                af[m], bfr[n], acc[m][n], 0, 0, 0);

        // all own LDS reads of buf[cur] complete -> free the buffer
        asm volatile("s_waitcnt lgkmcnt(0)" ::: "memory");
        __builtin_amdgcn_s_barrier();
        __builtin_amdgcn_sched_barrier(0);

        if (kt + 2 < 32) stage(cur, kt + 2);     // into freed buffer
        cur ^= 1;
    }

#pragma unroll
    for (int n = 0; n < 4; ++n) {
        const int col = col0 + wc + n * 16 + li;
        const float bv = bias[col];
#pragma unroll
        for (int m = 0; m < 4; ++m) {
            const int rbase = row0 + wr + m * 16 + 4 * lg;
            if (mode == 1) {
                u16* o = (u16*)out;
                const int h = col >> 6, dh = col & 63;
#pragma unroll
                for (int r = 0; r < 4; ++r) {
                    const int grow = rbase + r;
                    const int b = grow >= T ? 1 : 0;
                    const int t = grow - b * T;
                    o[(((size_t)b * NH + h) * T + t) * DHN + dh] =
                        f2bf(acc[m][n][r] + bv);
                }
            } else {
                u16* o = (u16*)out;
                const int h = col >> 6, dh = col & 63;
                const int b = rbase >= T ? 1 : 0;
                const int t = rbase - b * T;
                u16x4 pk;
                pk[0] = f2bf(acc[m][n][0] + bv);
                pk[1] = f2bf(acc[m][n][1] + bv);
                pk[2] = f2bf(acc[m][n][2] + bv);
                pk[3] = f2bf(acc[m][n][3] + bv);
                *(u16x4*)&o[(((size_t)b * NH + h) * DHN + dh) * (size_t)T + t] = pk;
            }
        }
    }
}

// Merged Q+K+V projections: 896 wg, XCD-bijective swizzle, id-decoded.
__global__ __launch_bounds__(256)
void gemm_qkv(const u16* __restrict__ xb, const u16* __restrict__ memb,
              const u16* __restrict__ Wq, const float* __restrict__ bq, u16* Qb,
              const u16* __restrict__ Wk, const float* __restrict__ bk, u16* Kb,
              const u16* __restrict__ Wv, const float* __restrict__ bv, u16* Vtb)
{
    __shared__ u16 As[2][128 * 32];
    __shared__ u16 Bs[2][128 * 32];
    const int id = (blockIdx.x & 7) * 112 + (blockIdx.x >> 3);  // 896 = 8*112
    if (id < 256) {
        gemm_body(xb, nullptr, Wq, bq, Qb, SQ, 0, 1, id & 31, id >> 5,
                  As[0], As[1], Bs[0], Bs[1]);
    } else if (id < 576) {
        const int t = id - 256;
        gemm_body(xb, memb, Wk, bk, Kb, SKVN, SMEM, 1, t % 40, t / 40,
                  As[0], As[1], Bs[0], Bs[1]);
    } else {
        const int t = id - 576;
        gemm_body(xb, memb, Wv, bv, Vtb, SKVN, SMEM, 2, t % 40, t / 40,
                  As[0], As[1], Bs[0], Bs[1]);
    }
}

// ---------------------------------------------------------------------------
// O-projection: 64x128 tiles -> 512 wgs, counted-vmcnt ledger (3 ops/wave).
// ---------------------------------------------------------------------------
__global__ __launch_bounds__(256)
void gemm_o(const u16* __restrict__ x, const u16* __restrict__ W,
            const float* __restrict__ bias, float* __restrict__ out)
{
    __shared__ u16 As[2][64 * 32];
    __shared__ u16 Bs[2][128 * 32];

    const int tid  = threadIdx.x;
    const int wave = tid >> 6, lane = tid & 63;
    const int lg = lane >> 4, li = lane & 15;
    const int wr = (wave >> 1) * 32, wc = (wave & 1) * 64;

    const int id = (blockIdx.x & 7) * 64 + (blockIdx.x >> 3);   // 512 = 8*64
    const int row0 = (id >> 3) * 64, col0 = (id & 7) * 128;

    const int srow = lane >> 2;
    const int sslot = lane & 3;

    f32x4 acc[2][4];
    const f32x4 zf = {0.f, 0.f, 0.f, 0.f};
#pragma unroll
    for (int m = 0; m < 2; ++m)
#pragma unroll
        for (int n = 0; n < 4; ++n) acc[m][n] = zf;

    auto stage = [&](int c, int kt) {            // exactly 3 vmem ops per wave
        const int k0 = kt * 32;
        {   // A: 4 chunks of 16 rows; one per wave
            const int r = wave * 16 + srow;
            const int gs = sslot ^ ((r ^ (r >> 2)) & 3);
            async16(&As[c][wave * 512],
                    x + (size_t)(row0 + r) * ND + k0 + gs * 8);
        }
#pragma unroll
        for (int ch = wave; ch < 8; ch += 4) {   // B: 8 chunks; two per wave
            const int r = ch * 16 + srow;
            const int gs = sslot ^ ((r ^ (r >> 2)) & 3);
            async16(&Bs[c][ch * 512],
                    W + (size_t)(col0 + r) * ND + k0 + gs * 8);
        }
    };

    stage(0, 0);
    __builtin_amdgcn_sched_barrier(0);
    stage(1, 1);
    __builtin_amdgcn_sched_barrier(0);

    int cur = 0;
    for (int kt = 0; kt < 32; ++kt) {
        if (kt == 31) asm volatile("s_waitcnt vmcnt(0)" ::: "memory");
        else          asm volatile("s_waitcnt vmcnt(3)" ::: "memory");
        __builtin_amdgcn_s_barrier();
        __builtin_amdgcn_sched_barrier(0);

        bf16x8 af[2], bfr[4];
#pragma unroll
        for (int m = 0; m < 2; ++m) {
            const int r = wr + m * 16 + li;
            af[m] = *(const bf16x8*)&As[cur][r * 32 + ((lg ^ ((r ^ (r >> 2)) & 3)) << 3)];
        }
#pragma unroll
        for (int n = 0; n < 4; ++n) {
            const int r = wc + n * 16 + li;
            bfr[n] = *(const bf16x8*)&Bs[cur][r * 32 + ((lg ^ ((r ^ (r >> 2)) & 3)) << 3)];
        }
#pragma unroll
        for (int m = 0; m < 2; ++m)
#pragma unroll
            for (int n = 0; n < 4; ++n)
                acc[m][n] = __builtin_amdgcn_mfma_f32_16x16x32_bf16(
                                af[m], bfr[n], acc[m][n], 0, 0, 0);

        asm volatile("s_waitcnt lgkmcnt(0)" ::: "memory");
        __builtin_amdgcn_s_barrier();
        __builtin_amdgcn_sched_barrier(0);

        if (kt + 2 < 32) stage(cur, kt + 2);
        cur ^= 1;
    }

#pragma unroll
    for (int n = 0; n < 4; ++n) {
        const int col = col0 + wc + n * 16 + li;
        const float bv = bias[col];
#pragma unroll
        for (int m = 0; m < 2; ++m) {
            const int rbase = row0 + wr + m * 16 + 4 * lg;
#pragma unroll
            for (int r = 0; r < 4; ++r)
                out[(size_t)(rbase + r) * ND + col] = acc[m][n][r] + bv;
        }
    }
}

// ---------------------------------------------------------------------------
// MFMA flash attention (R14 config, verbatim — verified 71.7 us): 8 waves /
// 512 threads, Q-tile 256/block, 256 wgs; counted-vmcnt ledger (2 ops/wave).
// ---------------------------------------------------------------------------
__global__ __launch_bounds__(512)
void attn_mfma(const u16* __restrict__ Qw, const u16* __restrict__ Kw,
               const u16* __restrict__ Vt, const u16* __restrict__ mb16,
               u16* __restrict__ AO)
{
    __shared__ u16 Ks[2][64 * 64];
    __shared__ u16 Vs[2][64 * 64];
    __shared__ u16 Ps[8][2048];          // per-wave: 2 P^T tiles [64 kv][16 q]
    __shared__ u16 Ms[SKVN];             // bf16 mask bias row (5 KB)

    const int tid  = threadIdx.x;
    const int wave = tid >> 6, lane = tid & 63;
    const int lg = lane >> 4, li = lane & 15;

    const int wg = blockIdx.x;                   // 256 wgs
    const int sw = (wg & 7) * 32 + (wg >> 3);    // XCD-contiguous chunks
    const int bh = sw >> 3;                      // 8 q-tiles per bh
    const int q0 = (sw & 7) * 256;
    const int b = bh >> 4, h = bh & 15;

    const u16* Kg = Kw + (size_t)bh * SKVN * DHN;
    const u16* Vg = Vt + (size_t)bh * DHN * SKVN;
    const u16* m16row = mb16 + (size_t)b * SKVN;

    // Q fragments: rows q0 + wave*32 + li (half A) and +16 (half B)
    bf16x8 qA0, qA1, qB0, qB1;
    {
        const u16* Qp = Qw + ((size_t)bh * SQ + q0 + wave * 32 + li) * DHN;
        qA0 = *(const bf16x8*)(Qp + lg * 8);
        qA1 = *(const bf16x8*)(Qp + 32 + lg * 8);
        qB0 = *(const bf16x8*)(Qp + 16 * DHN + lg * 8);
        qB1 = *(const bf16x8*)(Qp + 16 * DHN + 32 + lg * 8);
    }

    // stage mask-bias row into LDS (one-time; fully drained by syncthreads)
    for (int i = tid * 8; i < SKVN; i += 4096)
        *(u16x8*)&Ms[i] = *(const u16x8*)(m16row + i);

    U8 ou;
#pragma unroll
    for (int i = 0; i < 4; ++i) { ou.p.lo[i] = 0x3F80; ou.p.hi[i] = 0x3F80; }
    const bf16x8 onesb = ou.v;

    const int srow = lane >> 3, sslot = lane & 7;

    auto stage = [&](int c, int t) {             // exactly 2 vmem ops per wave
        const int kv0 = t * 64;
        const int r = wave * 8 + srow;           // 8 waves cover 8 chunks
        async16(&Ks[c][wave * 512],
                Kg + (size_t)(kv0 + r) * DHN + ((sslot ^ (r & 7)) << 3));
        async16(&Vs[c][wave * 512],
                Vg + (size_t)r * SKVN + kv0 + ((sslot ^ (r & 7)) << 3));
    };

    f32x4 oA[4], oB[4], laccA, laccB;
    const f32x4 zf = {0.f, 0.f, 0.f, 0.f};
#pragma unroll
    for (int n = 0; n < 4; ++n) { oA[n] = zf; oB[n] = zf; }
    laccA = zf; laccB = zf;

    u16* Pw = &Ps[wave][0];
    const unsigned paA = lds_off(Pw) + 256u * lg + 8u * li;
    const unsigned paB = paA + 2048u;            // half-B P^T tile

    // Drain EVERYTHING (Q loads, mask staging) so the ledger starts clean.
    __syncthreads();
    __builtin_amdgcn_sched_barrier(0);
    stage(0, 0);                                 // S0: 2 ops
    __builtin_amdgcn_sched_barrier(0);
    stage(1, 1);                                 // S1: 2 ops
    __builtin_amdgcn_sched_barrier(0);

    const int NT = SKVN / 64;
    int cur = 0;
    for (int t = 0; t < NT; ++t) {
        // Drain stage(t): outstanding = [S(t)(2), S(t+1)(2)] -> vmcnt(2).
        // Last iteration has no S(t+1) in flight -> full drain.
        if (t == NT - 1) asm volatile("s_waitcnt vmcnt(0)" ::: "memory");
        else             asm volatile("s_waitcnt vmcnt(2)" ::: "memory");
        __builtin_amdgcn_s_barrier();
        __builtin_amdgcn_sched_barrier(0);

        // mask bias for this tile from LDS (broadcast reads)
        float mbc[4];
#pragma unroll
        for (int n = 0; n < 4; ++n)
            mbc[n] = bf2f(Ms[t * 64 + n * 16 + li]);

        // ---- S = Q K^T for both halves (K frags read once) ----
        __builtin_amdgcn_s_setprio(1);
        f32x4 sA[4], sB[4];
#pragma unroll
        for (int n = 0; n < 4; ++n) {
            const int r = n * 16 + li;
            bf16x8 kb0 = *(const bf16x8*)&Ks[cur][r * 64 + ((lg ^ (r & 7)) << 3)];
            bf16x8 kb1 = *(const bf16x8*)&Ks[cur][r * 64 + (((4 + lg) ^ (r & 7)) << 3)];
            f32x4 z = zf;
            z     = __builtin_amdgcn_mfma_f32_16x16x32_bf16(qA0, kb0, z, 0, 0, 0);
            sA[n] = __builtin_amdgcn_mfma_f32_16x16x32_bf16(qA1, kb1, z, 0, 0, 0);
            f32x4 y = zf;
            y     = __builtin_amdgcn_mfma_f32_16x16x32_bf16(qB0, kb0, y, 0, 0, 0);
            sB[n] = __builtin_amdgcn_mfma_f32_16x16x32_bf16(qB1, kb1, y, 0, 0, 0);
        }
        __builtin_amdgcn_s_setprio(0);

        // ---- P = exp2(s*CSC - mb); pack to the two P^T tiles ----
#pragma unroll
        for (int n = 0; n < 4; ++n) {
            const float mb = mbc[n];
            const int pw = (n * 16 + li) * 16 + lg * 4;
            PKU ua;
            ua.u[0] = cvtpk(exp2r(fmaf(sA[n][0], CSC, -mb)),
                            exp2r(fmaf(sA[n][1], CSC, -mb)));
            ua.u[1] = cvtpk(exp2r(fmaf(sA[n][2], CSC, -mb)),
                            exp2r(fmaf(sA[n][3], CSC, -mb)));
            *(u16x4*)&Pw[pw] = ua.v;
            PKU ub;
            ub.u[0] = cvtpk(exp2r(fmaf(sB[n][0], CSC, -mb)),
                            exp2r(fmaf(sB[n][1], CSC, -mb)));
            ub.u[1] = cvtpk(exp2r(fmaf(sB[n][2], CSC, -mb)),
                            exp2r(fmaf(sB[n][3], CSC, -mb)));
            *(u16x4*)&Pw[1024 + pw] = ub.v;
        }

        // ---- PV: A-frags via hardware transpose reads of both P^T tiles ----
        u16x4 a00 = tr_read(paA);
        u16x4 a01 = tr_read(paA + 128);
        u16x4 a10 = tr_read(paA + 1024);
        u16x4 a11 = tr_read(paA + 1024 + 128);
        u16x4 b00 = tr_read(paB);
        u16x4 b01 = tr_read(paB + 128);
        u16x4 b10 = tr_read(paB + 1024);
        u16x4 b11 = tr_read(paB + 1024 + 128);
        asm volatile("s_waitcnt lgkmcnt(0)" ::: "memory");
        __builtin_amdgcn_sched_barrier(0);
        U8 pA0, pA1, pB0, pB1;
        pA0.p.lo = a00; pA0.p.hi = a01;
        pA1.p.lo = a10; pA1.p.hi = a11;
        pB0.p.lo = b00; pB0.p.hi = b01;
        pB1.p.lo = b10; pB1.p.hi = b11;

        __builtin_amdgcn_s_setprio(1);
        laccA = __builtin_amdgcn_mfma_f32_16x16x32_bf16(pA0.v, onesb, laccA, 0, 0, 0);
        laccA = __builtin_amdgcn_mfma_f32_16x16x32_bf16(pA1.v, onesb, laccA, 0, 0, 0);
        laccB = __builtin_amdgcn_mfma_f32_16x16x32_bf16(pB0.v, onesb, laccB, 0, 0, 0);
        laccB = __builtin_amdgcn_mfma_f32_16x16x32_bf16(pB1.v, onesb, laccB, 0, 0, 0);
#pragma unroll
        for (int n = 0; n < 4; ++n) {
            const int r = n * 16 + li;
            bf16x8 vb0 = *(const bf16x8*)&Vs[cur][r * 64 + ((lg ^ (r & 7)) << 3)];
            bf16x8 vb1 = *(const bf16x8*)&Vs[cur][r * 64 + (((4 + lg) ^ (r & 7)) << 3)];
            oA[n] = __builtin_amdgcn_mfma_f32_16x16x32_bf16(pA0.v, vb0, oA[n], 0, 0, 0);
            oA[n] = __builtin_amdgcn_mfma_f32_16x16x32_bf16(pA1.v, vb1, oA[n], 0, 0, 0);
            oB[n] = __builtin_amdgcn_mfma_f32_16x16x32_bf16(pB0.v, vb0, oB[n], 0, 0, 0);
            oB[n] = __builtin_amdgcn_mfma_f32_16x16x32_bf16(pB1.v, vb1, oB[n], 0, 0, 0);
        }
        __builtin_amdgcn_s_setprio(0);

        // all own LDS reads of buf[cur] complete -> free the buffer
        asm volatile("s_waitcnt lgkmcnt(0)" ::: "memory");
        __builtin_amdgcn_s_barrier();
        __builtin_amdgcn_sched_barrier(0);

        if (t + 2 < NT) stage(cur, t + 2);       // S(t+2): 2 ops into freed buf
        cur ^= 1;
    }

    // epilogue: AO[b, q, h*64+d] bf16 — halves A and B
#pragma unroll
    for (int r = 0; r < 4; ++r) {
        const float invA = 1.f / laccA[r];
        const float invB = 1.f / laccB[r];
        const int rowA = q0 + wave * 32 + 4 * lg + r;
#pragma unroll
        for (int n = 0; n < 4; ++n) {
            const int col = h * DHN + n * 16 + li;
            AO[((size_t)b * SQ + rowA) * ND + col] = f2bf(oA[n][r] * invA);
            AO[((size_t)b * SQ + rowA + 16) * ND + col] = f2bf(oB[n][r] * invB);
        }
    }
}

// ---------------------------------------------------------------------------
extern "C" void kernel_launch(void* const* d_in, const int* in_sizes, int n_in,
                              void* d_out, int out_size, void* d_ws, size_t ws_size,
                              hipStream_t stream)
{
    const float* x    = (const float*)d_in[0];
    const float* mems = (const float*)d_in[1];
    const int*   mask = (const int*)d_in[3];
    const float* Wq = (const float*)d_in[4];  const float* bq = (const float*)d_in[5];
    const float* Wk = (const float*)d_in[6];  const float* bk = (const float*)d_in[7];
    const float* Wv = (const float*)d_in[8];  const float* bv = (const float*)d_in[9];
    const float* Wo = (const float*)d_in[10]; const float* bo = (const float*)d_in[11];
    float* out = (float*)d_out;

    u16* ws = (u16*)d_ws;
    u16* xb   = ws;
    u16* memb = xb   + (size_t)NB * SQ * ND;
    u16* Wqb  = memb + (size_t)NB * SMEM * ND;
    u16* Wkb  = Wqb + (size_t)ND * ND;
    u16* Wvb  = Wkb + (size_t)ND * ND;
    u16* Wob  = Wvb + (size_t)ND * ND;
    u16* Qb   = Wob + (size_t)ND * ND;
    u16* Kb   = Qb  + (size_t)NB * NH * SQ * DHN;
    u16* Vtb  = Kb  + (size_t)NB * NH * SKVN * DHN;
    u16* AOb  = Vtb + (size_t)NB * NH * SKVN * DHN;
    u16* mb16 = AOb + (size_t)NB * SQ * ND;

    const dim3 blk(256);
    cvt_all<<<dim3(4628), blk, 0, stream>>>(x, mems, Wq, Wk, Wv, Wo,
                                            xb, memb, Wqb, Wkb, Wvb, Wob,
                                            mask, mb16);
    gemm_qkv<<<dim3(896), blk, 0, stream>>>(xb, memb,
                                            Wqb, bq, Qb,
                                            Wkb, bk, Kb,
                                            Wvb, bv, Vtb);
    attn_mfma<<<dim3(256), dim3(512), 0, stream>>>(Qb, Kb, Vtb, mb16, AOb);
    gemm_o<<<dim3(512), blk, 0, stream>>>(AOb, Wob, bo, out);
}

// Round 17
// 157.700 us; speedup vs baseline: 1.0545x; 1.0291x over previous
//
#include <hip/hip_runtime.h>
#include <math.h>

#define NB   2
#define SQ   2048
#define SMEM 512
#define SKVN 2560
#define ND   1024
#define NH   16
#define DHN  64
#define NBH  32                     /* NB*NH */

typedef unsigned short u16;
typedef short bf16x8 __attribute__((ext_vector_type(8)));   // 8 bf16 = 4 VGPR
typedef float f32x4 __attribute__((ext_vector_type(4)));
typedef u16 u16x4 __attribute__((ext_vector_type(4)));
typedef u16 u16x8 __attribute__((ext_vector_type(8)));

#define CSC   0.1803368801111204f   /* 0.125 * log2(e) */

__device__ __forceinline__ u16 f2bf(float f) {             // RNE f32->bf16
    unsigned u = __float_as_uint(f);
    u += 0x7FFFu + ((u >> 16) & 1u);
    return (u16)(u >> 16);
}

__device__ __forceinline__ float bf2f(u16 v) {
    return __uint_as_float(((unsigned)v) << 16);
}

__device__ __forceinline__ void async16(u16* lds, const u16* g) {
    __builtin_amdgcn_global_load_lds(
        (const __attribute__((address_space(1))) void*)g,
        (__attribute__((address_space(3))) void*)lds, 16, 0, 0);
}

__device__ __forceinline__ unsigned lds_off(const void* p) {
    return (unsigned)(uintptr_t)(const __attribute__((address_space(3))) void*)p;
}

__device__ __forceinline__ u16x4 tr_read(unsigned a) {     // ds_read_b64_tr_b16
    u16x4 d;
    asm volatile("ds_read_b64_tr_b16 %0, %1" : "=v"(d) : "v"(a) : "memory");
    return d;
}

__device__ __forceinline__ unsigned cvtpk(float lo, float hi) {
    unsigned r;
    asm("v_cvt_pk_bf16_f32 %0, %1, %2" : "=v"(r) : "v"(lo), "v"(hi));
    return r;
}

__device__ __forceinline__ float exp2r(float x) {          // raw v_exp_f32
    float r;
    asm("v_exp_f32 %0, %1" : "=v"(r) : "v"(x));
    return r;
}

union PKU { unsigned u[2]; u16x4 v; };
union U8  { struct { u16x4 lo, hi; } p; bf16x8 v; };

// ---------------------------------------------------------------------------
// One launch: f32->bf16 for x, mems, Wq, Wk, Wv, Wo (+ mask -> bf16 log2-bias).
// ---------------------------------------------------------------------------
__global__ __launch_bounds__(256)
void cvt_all(const float* __restrict__ x, const float* __restrict__ mems,
             const float* __restrict__ W0, const float* __restrict__ W1,
             const float* __restrict__ W2, const float* __restrict__ W3,
             u16* __restrict__ xb, u16* __restrict__ memb,
             u16* __restrict__ d0, u16* __restrict__ d1,
             u16* __restrict__ d2, u16* __restrict__ d3,
             const int* __restrict__ mask, u16* __restrict__ mb16)
{
    const int bid = blockIdx.x;
    if (bid >= 4608) {                       // mask bias tail: 5120 elems
        const int i = (bid - 4608) * 256 + threadIdx.x;
        if (i < NB * SKVN)
            mb16[i] = mask[i] ? (u16)0 : f2bf(1.0e6f * CSC);
        return;
    }
    size_t i = ((size_t)bid * 256 + threadIdx.x) * 8;
    const float* s; u16* d;
    if (i < 4194304) { s = x; d = xb; }
    else if (i < 5242880) { s = mems; d = memb; i -= 4194304; }
    else {
        size_t off = i - 5242880;
        const int wi = (int)(off >> 20);
        i = off & 1048575;
        switch (wi) {
            case 0:  s = W0; d = d0; break;
            case 1:  s = W1; d = d1; break;
            case 2:  s = W2; d = d2; break;
            default: s = W3; d = d3; break;
        }
    }
    float4 a = *(const float4*)(s + i);
    float4 b = *(const float4*)(s + i + 4);
    u16x8 o;
    o[0]=f2bf(a.x); o[1]=f2bf(a.y); o[2]=f2bf(a.z); o[3]=f2bf(a.w);
    o[4]=f2bf(b.x); o[5]=f2bf(b.y); o[6]=f2bf(b.z); o[7]=f2bf(b.w);
    *(u16x8*)(d + i) = o;
}

// A-row pointer with fused [mems; x] concat (NB=2 hardcoded)
__device__ __forceinline__ const u16* arow_ptr(const u16* x, const u16* mems,
                                               int grow, int T, int memLen) {
    int b = grow >= T ? 1 : 0;
    int t = grow - b * T;
    if (memLen > 0 && t < memLen)
        return mems + ((size_t)(b * memLen + t)) * ND;
    return x + ((size_t)(b * (T - memLen) + (t - memLen))) * ND;
}

// ---------------------------------------------------------------------------
// bf16 GEMM body (R16 counted-vmcnt form, verified).
// ---------------------------------------------------------------------------
__device__ __forceinline__
void gemm_body(const u16* __restrict__ x, const u16* __restrict__ mems,
               const u16* __restrict__ W, const float* __restrict__ bias,
               void* __restrict__ out, int T, int memLen, int mode,
               int bx, int by, u16* As0, u16* As1, u16* Bs0, u16* Bs1)
{
    u16* As[2] = {As0, As1};
    u16* Bs[2] = {Bs0, Bs1};

    const int tid  = threadIdx.x;
    const int wave = tid >> 6, lane = tid & 63;
    const int lg = lane >> 4, li = lane & 15;
    const int wr = (wave >> 1) * 64, wc = (wave & 1) * 64;
    const int row0 = bx * 128, col0 = by * 128;

    const int srow = lane >> 2;
    const int sslot = lane & 3;

    f32x4 acc[4][4];
    const f32x4 zf = {0.f, 0.f, 0.f, 0.f};
#pragma unroll
    for (int m = 0; m < 4; ++m)
#pragma unroll
        for (int n = 0; n < 4; ++n) acc[m][n] = zf;

    auto stage = [&](int c, int kt) {            // exactly 4 vmem ops per wave
        const int k0 = kt * 32;
#pragma unroll
        for (int ch = wave; ch < 8; ch += 4) {
            const int r = ch * 16 + srow;
            const int gs = sslot ^ ((r ^ (r >> 2)) & 3);
            async16(&As[c][ch * 512],
                    arow_ptr(x, mems, row0 + r, T, memLen) + k0 + gs * 8);
        }
#pragma unroll
        for (int ch = wave; ch < 8; ch += 4) {
            const int r = ch * 16 + srow;
            const int gs = sslot ^ ((r ^ (r >> 2)) & 3);
            async16(&Bs[c][ch * 512],
                    W + (size_t)(col0 + r) * ND + k0 + gs * 8);
        }
    };

    stage(0, 0);
    __builtin_amdgcn_sched_barrier(0);
    stage(1, 1);
    __builtin_amdgcn_sched_barrier(0);

    int cur = 0;
    for (int kt = 0; kt < 32; ++kt) {
        if (kt == 31) asm volatile("s_waitcnt vmcnt(0)" ::: "memory");
        else          asm volatile("s_waitcnt vmcnt(4)" ::: "memory");
        __builtin_amdgcn_s_barrier();
        __builtin_amdgcn_sched_barrier(0);

        bf16x8 af[4], bfr[4];
#pragma unroll
        for (int m = 0; m < 4; ++m) {
            const int r = wr + m * 16 + li;
            af[m] = *(const bf16x8*)&As[cur][r * 32 + ((lg ^ ((r ^ (r >> 2)) & 3)) << 3)];
        }
#pragma unroll
        for (int n = 0; n < 4; ++n) {
            const int r = wc + n * 16 + li;
            bfr[n] = *(const bf16x8*)&Bs[cur][r * 32 + ((lg ^ ((r ^ (r >> 2)) & 3)) << 3)];
        }
#pragma unroll
        for (int m = 0; m < 4; ++m)
#pragma unroll
            for (int n = 0; n < 4; ++n)
                acc[m][n] = __builtin_amdgcn_mfma_f32_16x16x32_bf16(
                                af[m], bfr[n], acc[m][n], 0, 0, 0);

        asm volatile("s_waitcnt lgkmcnt(0)" ::: "memory");
        __builtin_amdgcn_s_barrier();
        __builtin_amdgcn_sched_barrier(0);

        if (kt + 2 < 32) stage(cur, kt + 2);
        cur ^= 1;
    }

#pragma unroll
    for (int n = 0; n < 4; ++n) {
        const int col = col0 + wc + n * 16 + li;
        const float bv = bias[col];
#pragma unroll
        for (int m = 0; m < 4; ++m) {
            const int rbase = row0 + wr + m * 16 + 4 * lg;
            if (mode == 1) {
                u16* o = (u16*)out;
                const int h = col >> 6, dh = col & 63;
#pragma unroll
                for (int r = 0; r < 4; ++r) {
                    const int grow = rbase + r;
                    const int b = grow >= T ? 1 : 0;
                    const int t = grow - b * T;
                    o[(((size_t)b * NH + h) * T + t) * DHN + dh] =
                        f2bf(acc[m][n][r] + bv);
                }
            } else {
                u16* o = (u16*)out;
                const int h = col >> 6, dh = col & 63;
                const int b = rbase >= T ? 1 : 0;
                const int t = rbase - b * T;
                u16x4 pk;
                pk[0] = f2bf(acc[m][n][0] + bv);
                pk[1] = f2bf(acc[m][n][1] + bv);
                pk[2] = f2bf(acc[m][n][2] + bv);
                pk[3] = f2bf(acc[m][n][3] + bv);
                *(u16x4*)&o[(((size_t)b * NH + h) * DHN + dh) * (size_t)T + t] = pk;
            }
        }
    }
}

// Merged Q+K+V projections: 896 wg, XCD-bijective swizzle, id-decoded.
__global__ __launch_bounds__(256)
void gemm_qkv(const u16* __restrict__ xb, const u16* __restrict__ memb,
              const u16* __restrict__ Wq, const float* __restrict__ bq, u16* Qb,
              const u16* __restrict__ Wk, const float* __restrict__ bk, u16* Kb,
              const u16* __restrict__ Wv, const float* __restrict__ bv, u16* Vtb)
{
    __shared__ u16 As[2][128 * 32];
    __shared__ u16 Bs[2][128 * 32];
    const int id = (blockIdx.x & 7) * 112 + (blockIdx.x >> 3);  // 896 = 8*112
    if (id < 256) {
        gemm_body(xb, nullptr, Wq, bq, Qb, SQ, 0, 1, id & 31, id >> 5,
                  As[0], As[1], Bs[0], Bs[1]);
    } else if (id < 576) {
        const int t = id - 256;
        gemm_body(xb, memb, Wk, bk, Kb, SKVN, SMEM, 1, t % 40, t / 40,
                  As[0], As[1], Bs[0], Bs[1]);
    } else {
        const int t = id - 576;
        gemm_body(xb, memb, Wv, bv, Vtb, SKVN, SMEM, 2, t % 40, t / 40,
                  As[0], As[1], Bs[0], Bs[1]);
    }
}

// ---------------------------------------------------------------------------
// O-projection: 64x128 tiles -> 512 wgs, counted-vmcnt ledger (3 ops/wave).
// ---------------------------------------------------------------------------
__global__ __launch_bounds__(256)
void gemm_o(const u16* __restrict__ x, const u16* __restrict__ W,
            const float* __restrict__ bias, float* __restrict__ out)
{
    __shared__ u16 As[2][64 * 32];
    __shared__ u16 Bs[2][128 * 32];

    const int tid  = threadIdx.x;
    const int wave = tid >> 6, lane = tid & 63;
    const int lg = lane >> 4, li = lane & 15;
    const int wr = (wave >> 1) * 32, wc = (wave & 1) * 64;

    const int id = (blockIdx.x & 7) * 64 + (blockIdx.x >> 3);   // 512 = 8*64
    const int row0 = (id >> 3) * 64, col0 = (id & 7) * 128;

    const int srow = lane >> 2;
    const int sslot = lane & 3;

    f32x4 acc[2][4];
    const f32x4 zf = {0.f, 0.f, 0.f, 0.f};
#pragma unroll
    for (int m = 0; m < 2; ++m)
#pragma unroll
        for (int n = 0; n < 4; ++n) acc[m][n] = zf;

    auto stage = [&](int c, int kt) {            // exactly 3 vmem ops per wave
        const int k0 = kt * 32;
        {
            const int r = wave * 16 + srow;
            const int gs = sslot ^ ((r ^ (r >> 2)) & 3);
            async16(&As[c][wave * 512],
                    x + (size_t)(row0 + r) * ND + k0 + gs * 8);
        }
#pragma unroll
        for (int ch = wave; ch < 8; ch += 4) {
            const int r = ch * 16 + srow;
            const int gs = sslot ^ ((r ^ (r >> 2)) & 3);
            async16(&Bs[c][ch * 512],
                    W + (size_t)(col0 + r) * ND + k0 + gs * 8);
        }
    };

    stage(0, 0);
    __builtin_amdgcn_sched_barrier(0);
    stage(1, 1);
    __builtin_amdgcn_sched_barrier(0);

    int cur = 0;
    for (int kt = 0; kt < 32; ++kt) {
        if (kt == 31) asm volatile("s_waitcnt vmcnt(0)" ::: "memory");
        else          asm volatile("s_waitcnt vmcnt(3)" ::: "memory");
        __builtin_amdgcn_s_barrier();
        __builtin_amdgcn_sched_barrier(0);

        bf16x8 af[2], bfr[4];
#pragma unroll
        for (int m = 0; m < 2; ++m) {
            const int r = wr + m * 16 + li;
            af[m] = *(const bf16x8*)&As[cur][r * 32 + ((lg ^ ((r ^ (r >> 2)) & 3)) << 3)];
        }
#pragma unroll
        for (int n = 0; n < 4; ++n) {
            const int r = wc + n * 16 + li;
            bfr[n] = *(const bf16x8*)&Bs[cur][r * 32 + ((lg ^ ((r ^ (r >> 2)) & 3)) << 3)];
        }
#pragma unroll
        for (int m = 0; m < 2; ++m)
#pragma unroll
            for (int n = 0; n < 4; ++n)
                acc[m][n] = __builtin_amdgcn_mfma_f32_16x16x32_bf16(
                                af[m], bfr[n], acc[m][n], 0, 0, 0);

        asm volatile("s_waitcnt lgkmcnt(0)" ::: "memory");
        __builtin_amdgcn_s_barrier();
        __builtin_amdgcn_sched_barrier(0);

        if (kt + 2 < 32) stage(cur, kt + 2);
        cur ^= 1;
    }

#pragma unroll
    for (int n = 0; n < 4; ++n) {
        const int col = col0 + wc + n * 16 + li;
        const float bv = bias[col];
#pragma unroll
        for (int m = 0; m < 2; ++m) {
            const int rbase = row0 + wr + m * 16 + 4 * lg;
#pragma unroll
            for (int r = 0; r < 4; ++r)
                out[(size_t)(rbase + r) * ND + col] = acc[m][n][r] + bv;
        }
    }
}

// ---------------------------------------------------------------------------
// MFMA flash attention v12: 8 waves x 16 q-rows (single half per wave),
// Q-tile 128/block, 512 wgs = 2 blocks/CU = 16 waves/CU (2x TLP vs R14).
// Same verified ledger (2 vmem ops/wave, vmcnt(2), last-iter 0), same
// softmax / P^T / tr_read machinery — B-half deleted, grid doubled.
// ---------------------------------------------------------------------------
__global__ __launch_bounds__(512)
void attn_mfma(const u16* __restrict__ Qw, const u16* __restrict__ Kw,
               const u16* __restrict__ Vt, const u16* __restrict__ mb16,
               u16* __restrict__ AO)
{
    __shared__ u16 Ks[2][64 * 64];
    __shared__ u16 Vs[2][64 * 64];
    __shared__ u16 Ps[8][1024];          // per-wave P^T tile [64 kv][16 q]
    __shared__ u16 Ms[SKVN];             // bf16 mask bias row (5 KB)

    const int tid  = threadIdx.x;
    const int wave = tid >> 6, lane = tid & 63;
    const int lg = lane >> 4, li = lane & 15;

    const int wg = blockIdx.x;                   // 512 wgs
    const int sw = (wg & 7) * 64 + (wg >> 3);    // XCD-contiguous chunks
    const int bh = sw >> 4;                      // 16 q-tiles per bh
    const int q0 = (sw & 15) * 128;
    const int b = bh >> 4, h = bh & 15;

    const u16* Kg = Kw + (size_t)bh * SKVN * DHN;
    const u16* Vg = Vt + (size_t)bh * DHN * SKVN;
    const u16* m16row = mb16 + (size_t)b * SKVN;

    // Q fragments: rows q0 + wave*16 + li
    bf16x8 qA0, qA1;
    {
        const u16* Qp = Qw + ((size_t)bh * SQ + q0 + wave * 16 + li) * DHN;
        qA0 = *(const bf16x8*)(Qp + lg * 8);
        qA1 = *(const bf16x8*)(Qp + 32 + lg * 8);
    }

    // stage mask-bias row into LDS (one-time; fully drained by syncthreads)
    for (int i = tid * 8; i < SKVN; i += 4096)
        *(u16x8*)&Ms[i] = *(const u16x8*)(m16row + i);

    U8 ou;
#pragma unroll
    for (int i = 0; i < 4; ++i) { ou.p.lo[i] = 0x3F80; ou.p.hi[i] = 0x3F80; }
    const bf16x8 onesb = ou.v;

    const int srow = lane >> 3, sslot = lane & 7;

    auto stage = [&](int c, int t) {             // exactly 2 vmem ops per wave
        const int kv0 = t * 64;
        const int r = wave * 8 + srow;           // 8 waves cover 8 chunks
        async16(&Ks[c][wave * 512],
                Kg + (size_t)(kv0 + r) * DHN + ((sslot ^ (r & 7)) << 3));
        async16(&Vs[c][wave * 512],
                Vg + (size_t)r * SKVN + kv0 + ((sslot ^ (r & 7)) << 3));
    };

    f32x4 oA[4], laccA;
    const f32x4 zf = {0.f, 0.f, 0.f, 0.f};
#pragma unroll
    for (int n = 0; n < 4; ++n) oA[n] = zf;
    laccA = zf;

    u16* Pw = &Ps[wave][0];
    const unsigned paA = lds_off(Pw) + 256u * lg + 8u * li;

    // Drain EVERYTHING (Q loads, mask staging) so the ledger starts clean.
    __syncthreads();
    __builtin_amdgcn_sched_barrier(0);
    stage(0, 0);                                 // S0: 2 ops
    __builtin_amdgcn_sched_barrier(0);
    stage(1, 1);                                 // S1: 2 ops
    __builtin_amdgcn_sched_barrier(0);

    const int NT = SKVN / 64;
    int cur = 0;
    for (int t = 0; t < NT; ++t) {
        // Drain stage(t): outstanding = [S(t)(2), S(t+1)(2)] -> vmcnt(2).
        if (t == NT - 1) asm volatile("s_waitcnt vmcnt(0)" ::: "memory");
        else             asm volatile("s_waitcnt vmcnt(2)" ::: "memory");
        __builtin_amdgcn_s_barrier();
        __builtin_amdgcn_sched_barrier(0);

        // mask bias for this tile from LDS (broadcast reads)
        float mbc[4];
#pragma unroll
        for (int n = 0; n < 4; ++n)
            mbc[n] = bf2f(Ms[t * 64 + n * 16 + li]);

        // ---- S = Q K^T (16 q-rows x 64 keys) ----
        __builtin_amdgcn_s_setprio(1);
        f32x4 sA[4];
#pragma unroll
        for (int n = 0; n < 4; ++n) {
            const int r = n * 16 + li;
            bf16x8 kb0 = *(const bf16x8*)&Ks[cur][r * 64 + ((lg ^ (r & 7)) << 3)];
            bf16x8 kb1 = *(const bf16x8*)&Ks[cur][r * 64 + (((4 + lg) ^ (r & 7)) << 3)];
            f32x4 z = zf;
            z     = __builtin_amdgcn_mfma_f32_16x16x32_bf16(qA0, kb0, z, 0, 0, 0);
            sA[n] = __builtin_amdgcn_mfma_f32_16x16x32_bf16(qA1, kb1, z, 0, 0, 0);
        }
        __builtin_amdgcn_s_setprio(0);

        // ---- P = exp2(s*CSC - mb); pack to P^T [kv][q] ----
#pragma unroll
        for (int n = 0; n < 4; ++n) {
            const float mb = mbc[n];
            const int pw = (n * 16 + li) * 16 + lg * 4;
            PKU ua;
            ua.u[0] = cvtpk(exp2r(fmaf(sA[n][0], CSC, -mb)),
                            exp2r(fmaf(sA[n][1], CSC, -mb)));
            ua.u[1] = cvtpk(exp2r(fmaf(sA[n][2], CSC, -mb)),
                            exp2r(fmaf(sA[n][3], CSC, -mb)));
            *(u16x4*)&Pw[pw] = ua.v;
        }

        // ---- PV: A-frags via hardware transpose reads of P^T ----
        u16x4 a00 = tr_read(paA);
        u16x4 a01 = tr_read(paA + 128);
        u16x4 a10 = tr_read(paA + 1024);
        u16x4 a11 = tr_read(paA + 1024 + 128);
        asm volatile("s_waitcnt lgkmcnt(0)" ::: "memory");
        __builtin_amdgcn_sched_barrier(0);
        U8 pA0, pA1;
        pA0.p.lo = a00; pA0.p.hi = a01;
        pA1.p.lo = a10; pA1.p.hi = a11;

        __builtin_amdgcn_s_setprio(1);
        laccA = __builtin_amdgcn_mfma_f32_16x16x32_bf16(pA0.v, onesb, laccA, 0, 0, 0);
        laccA = __builtin_amdgcn_mfma_f32_16x16x32_bf16(pA1.v, onesb, laccA, 0, 0, 0);
#pragma unroll
        for (int n = 0; n < 4; ++n) {
            const int r = n * 16 + li;
            bf16x8 vb0 = *(const bf16x8*)&Vs[cur][r * 64 + ((lg ^ (r & 7)) << 3)];
            bf16x8 vb1 = *(const bf16x8*)&Vs[cur][r * 64 + (((4 + lg) ^ (r & 7)) << 3)];
            oA[n] = __builtin_amdgcn_mfma_f32_16x16x32_bf16(pA0.v, vb0, oA[n], 0, 0, 0);
            oA[n] = __builtin_amdgcn_mfma_f32_16x16x32_bf16(pA1.v, vb1, oA[n], 0, 0, 0);
        }
        __builtin_amdgcn_s_setprio(0);

        // all own LDS reads of buf[cur] complete -> free the buffer
        asm volatile("s_waitcnt lgkmcnt(0)" ::: "memory");
        __builtin_amdgcn_s_barrier();
        __builtin_amdgcn_sched_barrier(0);

        if (t + 2 < NT) stage(cur, t + 2);       // S(t+2): 2 ops into freed buf
        cur ^= 1;
    }

    // epilogue: AO[b, q, h*64+d] bf16
#pragma unroll
    for (int r = 0; r < 4; ++r) {
        const float invA = 1.f / laccA[r];
        const int rowA = q0 + wave * 16 + 4 * lg + r;
#pragma unroll
        for (int n = 0; n < 4; ++n) {
            const int col = h * DHN + n * 16 + li;
            AO[((size_t)b * SQ + rowA) * ND + col] = f2bf(oA[n][r] * invA);
        }
    }
}

// ---------------------------------------------------------------------------
extern "C" void kernel_launch(void* const* d_in, const int* in_sizes, int n_in,
                              void* d_out, int out_size, void* d_ws, size_t ws_size,
                              hipStream_t stream)
{
    const float* x    = (const float*)d_in[0];
    const float* mems = (const float*)d_in[1];
    const int*   mask = (const int*)d_in[3];
    const float* Wq = (const float*)d_in[4];  const float* bq = (const float*)d_in[5];
    const float* Wk = (const float*)d_in[6];  const float* bk = (const float*)d_in[7];
    const float* Wv = (const float*)d_in[8];  const float* bv = (const float*)d_in[9];
    const float* Wo = (const float*)d_in[10]; const float* bo = (const float*)d_in[11];
    float* out = (float*)d_out;

    u16* ws = (u16*)d_ws;
    u16* xb   = ws;
    u16* memb = xb   + (size_t)NB * SQ * ND;
    u16* Wqb  = memb + (size_t)NB * SMEM * ND;
    u16* Wkb  = Wqb + (size_t)ND * ND;
    u16* Wvb  = Wkb + (size_t)ND * ND;
    u16* Wob  = Wvb + (size_t)ND * ND;
    u16* Qb   = Wob + (size_t)ND * ND;
    u16* Kb   = Qb  + (size_t)NB * NH * SQ * DHN;
    u16* Vtb  = Kb  + (size_t)NB * NH * SKVN * DHN;
    u16* AOb  = Vtb + (size_t)NB * NH * SKVN * DHN;
    u16* mb16 = AOb + (size_t)NB * SQ * ND;

    const dim3 blk(256);
    cvt_all<<<dim3(4628), blk, 0, stream>>>(x, mems, Wq, Wk, Wv, Wo,
                                            xb, memb, Wqb, Wkb, Wvb, Wob,
                                            mask, mb16);
    gemm_qkv<<<dim3(896), blk, 0, stream>>>(xb, memb,
                                            Wqb, bq, Qb,
                                            Wkb, bk, Kb,
                                            Wvb, bv, Vtb);
    attn_mfma<<<dim3(512), dim3(512), 0, stream>>>(Qb, Kb, Vtb, mb16, AOb);
    gemm_o<<<dim3(512), blk, 0, stream>>>(AOb, Wob, bo, out);
}

// Round 18
// 150.020 us; speedup vs baseline: 1.1085x; 1.0512x over previous
//
#include <hip/hip_runtime.h>
#include <math.h>

#define NB   2
#define SQ   2048
#define SMEM 512
#define SKVN 2560
#define ND   1024
#define NH   16
#define DHN  64
#define NBH  32                     /* NB*NH */

typedef unsigned short u16;
typedef short bf16x8 __attribute__((ext_vector_type(8)));   // 8 bf16 = 4 VGPR
typedef float f32x4 __attribute__((ext_vector_type(4)));
typedef u16 u16x4 __attribute__((ext_vector_type(4)));
typedef u16 u16x8 __attribute__((ext_vector_type(8)));

#define CSC   0.1803368801111204f   /* 0.125 * log2(e) */

__device__ __forceinline__ u16 f2bf(float f) {             // RNE f32->bf16
    unsigned u = __float_as_uint(f);
    u += 0x7FFFu + ((u >> 16) & 1u);
    return (u16)(u >> 16);
}

__device__ __forceinline__ float bf2f(u16 v) {
    return __uint_as_float(((unsigned)v) << 16);
}

__device__ __forceinline__ void async16(u16* lds, const u16* g) {
    __builtin_amdgcn_global_load_lds(
        (const __attribute__((address_space(1))) void*)g,
        (__attribute__((address_space(3))) void*)lds, 16, 0, 0);
}

__device__ __forceinline__ unsigned lds_off(const void* p) {
    return (unsigned)(uintptr_t)(const __attribute__((address_space(3))) void*)p;
}

__device__ __forceinline__ u16x4 tr_read(unsigned a) {     // ds_read_b64_tr_b16
    u16x4 d;
    asm volatile("ds_read_b64_tr_b16 %0, %1" : "=v"(d) : "v"(a) : "memory");
    return d;
}

__device__ __forceinline__ unsigned cvtpk(float lo, float hi) {
    unsigned r;
    asm("v_cvt_pk_bf16_f32 %0, %1, %2" : "=v"(r) : "v"(lo), "v"(hi));
    return r;
}

__device__ __forceinline__ float exp2r(float x) {          // raw v_exp_f32
    float r;
    asm("v_exp_f32 %0, %1" : "=v"(r) : "v"(x));
    return r;
}

union PKU { unsigned u[2]; u16x4 v; };
union U8  { struct { u16x4 lo, hi; } p; bf16x8 v; };

// ---------------------------------------------------------------------------
// One launch: f32->bf16 for x, mems, Wq, Wk, Wv, Wo (+ mask -> bf16 log2-bias).
// ---------------------------------------------------------------------------
__global__ __launch_bounds__(256)
void cvt_all(const float* __restrict__ x, const float* __restrict__ mems,
             const float* __restrict__ W0, const float* __restrict__ W1,
             const float* __restrict__ W2, const float* __restrict__ W3,
             u16* __restrict__ xb, u16* __restrict__ memb,
             u16* __restrict__ d0, u16* __restrict__ d1,
             u16* __restrict__ d2, u16* __restrict__ d3,
             const int* __restrict__ mask, u16* __restrict__ mb16)
{
    const int bid = blockIdx.x;
    if (bid >= 4608) {                       // mask bias tail: 5120 elems
        const int i = (bid - 4608) * 256 + threadIdx.x;
        if (i < NB * SKVN)
            mb16[i] = mask[i] ? (u16)0 : f2bf(1.0e6f * CSC);
        return;
    }
    size_t i = ((size_t)bid * 256 + threadIdx.x) * 8;
    const float* s; u16* d;
    if (i < 4194304) { s = x; d = xb; }
    else if (i < 5242880) { s = mems; d = memb; i -= 4194304; }
    else {
        size_t off = i - 5242880;
        const int wi = (int)(off >> 20);
        i = off & 1048575;
        switch (wi) {
            case 0:  s = W0; d = d0; break;
            case 1:  s = W1; d = d1; break;
            case 2:  s = W2; d = d2; break;
            default: s = W3; d = d3; break;
        }
    }
    float4 a = *(const float4*)(s + i);
    float4 b = *(const float4*)(s + i + 4);
    u16x8 o;
    o[0]=f2bf(a.x); o[1]=f2bf(a.y); o[2]=f2bf(a.z); o[3]=f2bf(a.w);
    o[4]=f2bf(b.x); o[5]=f2bf(b.y); o[6]=f2bf(b.z); o[7]=f2bf(b.w);
    *(u16x8*)(d + i) = o;
}

// A-row pointer with fused [mems; x] concat (NB=2 hardcoded)
__device__ __forceinline__ const u16* arow_ptr(const u16* x, const u16* mems,
                                               int grow, int T, int memLen) {
    int b = grow >= T ? 1 : 0;
    int t = grow - b * T;
    if (memLen > 0 && t < memLen)
        return mems + ((size_t)(b * memLen + t)) * ND;
    return x + ((size_t)(b * (T - memLen) + (t - memLen))) * ND;
}

// ---------------------------------------------------------------------------
// Single-wave 64x64 GEMM body — NO barriers. One wave owns the block, a
// private double-buffered LDS pair, and a pure per-wave vmcnt ledger:
// stage() = exactly 8 vmem ops; wait vmcnt(8) (S(kt) landed, S(kt+1) in
// flight), last iter vmcnt(0); lgkmcnt(0) frees buf before restaging.
// Same verified both-sides swizzle and MFMA fragment formulas.
// mode 0: f32 [M,ND]; mode 1: bf16 [B,H,T,DH]; mode 2: bf16 [B,H,DH,T].
// ---------------------------------------------------------------------------
__device__ __forceinline__
void gemm64_body(const u16* __restrict__ x, const u16* __restrict__ mems,
                 const u16* __restrict__ W, const float* __restrict__ bias,
                 void* __restrict__ out, int T, int memLen, int mode,
                 int bx, int by, u16* As0, u16* As1, u16* Bs0, u16* Bs1)
{
    u16* As[2] = {As0, As1};
    u16* Bs[2] = {Bs0, Bs1};

    const int lane = threadIdx.x;        // 0..63
    const int lg = lane >> 4, li = lane & 15;
    const int row0 = bx * 64, col0 = by * 64;

    const int srow = lane >> 2;          // 0..15 row within 16-row chunk
    const int sslot = lane & 3;          // 16B slot within 64B row

    f32x4 acc[4][4];
    const f32x4 zf = {0.f, 0.f, 0.f, 0.f};
#pragma unroll
    for (int m = 0; m < 4; ++m)
#pragma unroll
        for (int n = 0; n < 4; ++n) acc[m][n] = zf;

    auto stage = [&](int c, int kt) {    // exactly 8 vmem ops per wave
        const int k0 = kt * 32;
#pragma unroll
        for (int ch = 0; ch < 4; ++ch) {
            const int r = ch * 16 + srow;
            const int gs = sslot ^ ((r ^ (r >> 2)) & 3);
            async16(&As[c][ch * 512],
                    arow_ptr(x, mems, row0 + r, T, memLen) + k0 + gs * 8);
        }
#pragma unroll
        for (int ch = 0; ch < 4; ++ch) {
            const int r = ch * 16 + srow;
            const int gs = sslot ^ ((r ^ (r >> 2)) & 3);
            async16(&Bs[c][ch * 512],
                    W + (size_t)(col0 + r) * ND + k0 + gs * 8);
        }
    };

    stage(0, 0);
    __builtin_amdgcn_sched_barrier(0);
    stage(1, 1);
    __builtin_amdgcn_sched_barrier(0);

    int cur = 0;
    for (int kt = 0; kt < 32; ++kt) {
        // outstanding = S(kt)(8) + [kt<31: S(kt+1)(8)]
        if (kt == 31) asm volatile("s_waitcnt vmcnt(0)" ::: "memory");
        else          asm volatile("s_waitcnt vmcnt(8)" ::: "memory");
        __builtin_amdgcn_sched_barrier(0);

        bf16x8 af[4], bfr[4];
#pragma unroll
        for (int m = 0; m < 4; ++m) {
            const int r = m * 16 + li;
            af[m] = *(const bf16x8*)&As[cur][r * 32 + ((lg ^ ((r ^ (r >> 2)) & 3)) << 3)];
        }
#pragma unroll
        for (int n = 0; n < 4; ++n) {
            const int r = n * 16 + li;
            bfr[n] = *(const bf16x8*)&Bs[cur][r * 32 + ((lg ^ ((r ^ (r >> 2)) & 3)) << 3)];
        }
        // own ds_reads drained -> buffer free; restage it, then compute.
        asm volatile("s_waitcnt lgkmcnt(0)" ::: "memory");
        __builtin_amdgcn_sched_barrier(0);
        if (kt + 2 < 32) stage(cur, kt + 2);

#pragma unroll
        for (int m = 0; m < 4; ++m)
#pragma unroll
            for (int n = 0; n < 4; ++n)
                acc[m][n] = __builtin_amdgcn_mfma_f32_16x16x32_bf16(
                                af[m], bfr[n], acc[m][n], 0, 0, 0);
        cur ^= 1;
    }

#pragma unroll
    for (int n = 0; n < 4; ++n) {
        const int col = col0 + n * 16 + li;
        const float bv = bias[col];
#pragma unroll
        for (int m = 0; m < 4; ++m) {
            const int rbase = row0 + m * 16 + 4 * lg;
            if (mode == 0) {
                float* o = (float*)out;
#pragma unroll
                for (int r = 0; r < 4; ++r)
                    o[(size_t)(rbase + r) * ND + col] = acc[m][n][r] + bv;
            } else if (mode == 1) {
                u16* o = (u16*)out;
                const int h = col >> 6, dh = col & 63;
#pragma unroll
                for (int r = 0; r < 4; ++r) {
                    const int grow = rbase + r;
                    const int b = grow >= T ? 1 : 0;
                    const int t = grow - b * T;
                    o[(((size_t)b * NH + h) * T + t) * DHN + dh] =
                        f2bf(acc[m][n][r] + bv);
                }
            } else {
                u16* o = (u16*)out;
                const int h = col >> 6, dh = col & 63;
                const int b = rbase >= T ? 1 : 0;
                const int t = rbase - b * T;
                u16x4 pk;
                pk[0] = f2bf(acc[m][n][0] + bv);
                pk[1] = f2bf(acc[m][n][1] + bv);
                pk[2] = f2bf(acc[m][n][2] + bv);
                pk[3] = f2bf(acc[m][n][3] + bv);
                *(u16x4*)&o[(((size_t)b * NH + h) * DHN + dh) * (size_t)T + t] = pk;
            }
        }
    }
}

// Q+K+V projections: 3584 single-wave blocks. A-panel-major decode (16
// consecutive ids share one 64-row A panel -> L2 reuse), XCD-bijective.
__global__ __launch_bounds__(64)
void gemm_qkv(const u16* __restrict__ xb, const u16* __restrict__ memb,
              const u16* __restrict__ Wq, const float* __restrict__ bq, u16* Qb,
              const u16* __restrict__ Wk, const float* __restrict__ bk, u16* Kb,
              const u16* __restrict__ Wv, const float* __restrict__ bv, u16* Vtb)
{
    __shared__ u16 As[2][64 * 32];
    __shared__ u16 Bs[2][64 * 32];
    const int id = (blockIdx.x & 7) * 448 + (blockIdx.x >> 3);  // 3584 = 8*448
    if (id < 1024) {                       // Q: 64 row-tiles x 16 col-tiles
        gemm64_body(xb, nullptr, Wq, bq, Qb, SQ, 0, 1, id >> 4, id & 15,
                    As[0], As[1], Bs[0], Bs[1]);
    } else if (id < 2304) {                // K: 80 x 16
        const int t = id - 1024;
        gemm64_body(xb, memb, Wk, bk, Kb, SKVN, SMEM, 1, t >> 4, t & 15,
                    As[0], As[1], Bs[0], Bs[1]);
    } else {                               // V: 80 x 16
        const int t = id - 2304;
        gemm64_body(xb, memb, Wv, bv, Vtb, SKVN, SMEM, 2, t >> 4, t & 15,
                    As[0], As[1], Bs[0], Bs[1]);
    }
}

// O-projection: 1024 single-wave blocks (64 x 16), XCD-bijective.
__global__ __launch_bounds__(64)
void gemm_o(const u16* __restrict__ x, const u16* __restrict__ W,
            const float* __restrict__ bias, float* __restrict__ out)
{
    __shared__ u16 As[2][64 * 32];
    __shared__ u16 Bs[2][64 * 32];
    const int id = (blockIdx.x & 7) * 128 + (blockIdx.x >> 3);  // 1024 = 8*128
    gemm64_body(x, nullptr, W, bias, out, SQ, 0, 0, id >> 4, id & 15,
                As[0], As[1], Bs[0], Bs[1]);
}

// ---------------------------------------------------------------------------
// MFMA flash attention (R17 config, verbatim — verified): 8 waves x 16 q-rows,
// Q-tile 128/block, 512 wgs; counted-vmcnt ledger (2 ops/wave).
// ---------------------------------------------------------------------------
__global__ __launch_bounds__(512)
void attn_mfma(const u16* __restrict__ Qw, const u16* __restrict__ Kw,
               const u16* __restrict__ Vt, const u16* __restrict__ mb16,
               u16* __restrict__ AO)
{
    __shared__ u16 Ks[2][64 * 64];
    __shared__ u16 Vs[2][64 * 64];
    __shared__ u16 Ps[8][1024];          // per-wave P^T tile [64 kv][16 q]
    __shared__ u16 Ms[SKVN];             // bf16 mask bias row (5 KB)

    const int tid  = threadIdx.x;
    const int wave = tid >> 6, lane = tid & 63;
    const int lg = lane >> 4, li = lane & 15;

    const int wg = blockIdx.x;                   // 512 wgs
    const int sw = (wg & 7) * 64 + (wg >> 3);    // XCD-contiguous chunks
    const int bh = sw >> 4;                      // 16 q-tiles per bh
    const int q0 = (sw & 15) * 128;
    const int b = bh >> 4, h = bh & 15;

    const u16* Kg = Kw + (size_t)bh * SKVN * DHN;
    const u16* Vg = Vt + (size_t)bh * DHN * SKVN;
    const u16* m16row = mb16 + (size_t)b * SKVN;

    // Q fragments: rows q0 + wave*16 + li
    bf16x8 qA0, qA1;
    {
        const u16* Qp = Qw + ((size_t)bh * SQ + q0 + wave * 16 + li) * DHN;
        qA0 = *(const bf16x8*)(Qp + lg * 8);
        qA1 = *(const bf16x8*)(Qp + 32 + lg * 8);
    }

    // stage mask-bias row into LDS (one-time; fully drained by syncthreads)
    for (int i = tid * 8; i < SKVN; i += 4096)
        *(u16x8*)&Ms[i] = *(const u16x8*)(m16row + i);

    U8 ou;
#pragma unroll
    for (int i = 0; i < 4; ++i) { ou.p.lo[i] = 0x3F80; ou.p.hi[i] = 0x3F80; }
    const bf16x8 onesb = ou.v;

    const int srow = lane >> 3, sslot = lane & 7;

    auto stage = [&](int c, int t) {             // exactly 2 vmem ops per wave
        const int kv0 = t * 64;
        const int r = wave * 8 + srow;           // 8 waves cover 8 chunks
        async16(&Ks[c][wave * 512],
                Kg + (size_t)(kv0 + r) * DHN + ((sslot ^ (r & 7)) << 3));
        async16(&Vs[c][wave * 512],
                Vg + (size_t)r * SKVN + kv0 + ((sslot ^ (r & 7)) << 3));
    };

    f32x4 oA[4], laccA;
    const f32x4 zf = {0.f, 0.f, 0.f, 0.f};
#pragma unroll
    for (int n = 0; n < 4; ++n) oA[n] = zf;
    laccA = zf;

    u16* Pw = &Ps[wave][0];
    const unsigned paA = lds_off(Pw) + 256u * lg + 8u * li;

    // Drain EVERYTHING (Q loads, mask staging) so the ledger starts clean.
    __syncthreads();
    __builtin_amdgcn_sched_barrier(0);
    stage(0, 0);                                 // S0: 2 ops
    __builtin_amdgcn_sched_barrier(0);
    stage(1, 1);                                 // S1: 2 ops
    __builtin_amdgcn_sched_barrier(0);

    const int NT = SKVN / 64;
    int cur = 0;
    for (int t = 0; t < NT; ++t) {
        // Drain stage(t): outstanding = [S(t)(2), S(t+1)(2)] -> vmcnt(2).
        if (t == NT - 1) asm volatile("s_waitcnt vmcnt(0)" ::: "memory");
        else             asm volatile("s_waitcnt vmcnt(2)" ::: "memory");
        __builtin_amdgcn_s_barrier();
        __builtin_amdgcn_sched_barrier(0);

        // mask bias for this tile from LDS (broadcast reads)
        float mbc[4];
#pragma unroll
        for (int n = 0; n < 4; ++n)
            mbc[n] = bf2f(Ms[t * 64 + n * 16 + li]);

        // ---- S = Q K^T (16 q-rows x 64 keys) ----
        __builtin_amdgcn_s_setprio(1);
        f32x4 sA[4];
#pragma unroll
        for (int n = 0; n < 4; ++n) {
            const int r = n * 16 + li;
            bf16x8 kb0 = *(const bf16x8*)&Ks[cur][r * 64 + ((lg ^ (r & 7)) << 3)];
            bf16x8 kb1 = *(const bf16x8*)&Ks[cur][r * 64 + (((4 + lg) ^ (r & 7)) << 3)];
            f32x4 z = zf;
            z     = __builtin_amdgcn_mfma_f32_16x16x32_bf16(qA0, kb0, z, 0, 0, 0);
            sA[n] = __builtin_amdgcn_mfma_f32_16x16x32_bf16(qA1, kb1, z, 0, 0, 0);
        }
        __builtin_amdgcn_s_setprio(0);

        // ---- P = exp2(s*CSC - mb); pack to P^T [kv][q] ----
#pragma unroll
        for (int n = 0; n < 4; ++n) {
            const float mb = mbc[n];
            const int pw = (n * 16 + li) * 16 + lg * 4;
            PKU ua;
            ua.u[0] = cvtpk(exp2r(fmaf(sA[n][0], CSC, -mb)),
                            exp2r(fmaf(sA[n][1], CSC, -mb)));
            ua.u[1] = cvtpk(exp2r(fmaf(sA[n][2], CSC, -mb)),
                            exp2r(fmaf(sA[n][3], CSC, -mb)));
            *(u16x4*)&Pw[pw] = ua.v;
        }

        // ---- PV: A-frags via hardware transpose reads of P^T ----
        u16x4 a00 = tr_read(paA);
        u16x4 a01 = tr_read(paA + 128);
        u16x4 a10 = tr_read(paA + 1024);
        u16x4 a11 = tr_read(paA + 1024 + 128);
        asm volatile("s_waitcnt lgkmcnt(0)" ::: "memory");
        __builtin_amdgcn_sched_barrier(0);
        U8 pA0, pA1;
        pA0.p.lo = a00; pA0.p.hi = a01;
        pA1.p.lo = a10; pA1.p.hi = a11;

        __builtin_amdgcn_s_setprio(1);
        laccA = __builtin_amdgcn_mfma_f32_16x16x32_bf16(pA0.v, onesb, laccA, 0, 0, 0);
        laccA = __builtin_amdgcn_mfma_f32_16x16x32_bf16(pA1.v, onesb, laccA, 0, 0, 0);
#pragma unroll
        for (int n = 0; n < 4; ++n) {
            const int r = n * 16 + li;
            bf16x8 vb0 = *(const bf16x8*)&Vs[cur][r * 64 + ((lg ^ (r & 7)) << 3)];
            bf16x8 vb1 = *(const bf16x8*)&Vs[cur][r * 64 + (((4 + lg) ^ (r & 7)) << 3)];
            oA[n] = __builtin_amdgcn_mfma_f32_16x16x32_bf16(pA0.v, vb0, oA[n], 0, 0, 0);
            oA[n] = __builtin_amdgcn_mfma_f32_16x16x32_bf16(pA1.v, vb1, oA[n], 0, 0, 0);
        }
        __builtin_amdgcn_s_setprio(0);

        // all own LDS reads of buf[cur] complete -> free the buffer
        asm volatile("s_waitcnt lgkmcnt(0)" ::: "memory");
        __builtin_amdgcn_s_barrier();
        __builtin_amdgcn_sched_barrier(0);

        if (t + 2 < NT) stage(cur, t + 2);       // S(t+2): 2 ops into freed buf
        cur ^= 1;
    }

    // epilogue: AO[b, q, h*64+d] bf16
#pragma unroll
    for (int r = 0; r < 4; ++r) {
        const float invA = 1.f / laccA[r];
        const int rowA = q0 + wave * 16 + 4 * lg + r;
#pragma unroll
        for (int n = 0; n < 4; ++n) {
            const int col = h * DHN + n * 16 + li;
            AO[((size_t)b * SQ + rowA) * ND + col] = f2bf(oA[n][r] * invA);
        }
    }
}

// ---------------------------------------------------------------------------
extern "C" void kernel_launch(void* const* d_in, const int* in_sizes, int n_in,
                              void* d_out, int out_size, void* d_ws, size_t ws_size,
                              hipStream_t stream)
{
    const float* x    = (const float*)d_in[0];
    const float* mems = (const float*)d_in[1];
    const int*   mask = (const int*)d_in[3];
    const float* Wq = (const float*)d_in[4];  const float* bq = (const float*)d_in[5];
    const float* Wk = (const float*)d_in[6];  const float* bk = (const float*)d_in[7];
    const float* Wv = (const float*)d_in[8];  const float* bv = (const float*)d_in[9];
    const float* Wo = (const float*)d_in[10]; const float* bo = (const float*)d_in[11];
    float* out = (float*)d_out;

    u16* ws = (u16*)d_ws;
    u16* xb   = ws;
    u16* memb = xb   + (size_t)NB * SQ * ND;
    u16* Wqb  = memb + (size_t)NB * SMEM * ND;
    u16* Wkb  = Wqb + (size_t)ND * ND;
    u16* Wvb  = Wkb + (size_t)ND * ND;
    u16* Wob  = Wvb + (size_t)ND * ND;
    u16* Qb   = Wob + (size_t)ND * ND;
    u16* Kb   = Qb  + (size_t)NB * NH * SQ * DHN;
    u16* Vtb  = Kb  + (size_t)NB * NH * SKVN * DHN;
    u16* AOb  = Vtb + (size_t)NB * NH * SKVN * DHN;
    u16* mb16 = AOb + (size_t)NB * SQ * ND;

    const dim3 blk(256);
    cvt_all<<<dim3(4628), blk, 0, stream>>>(x, mems, Wq, Wk, Wv, Wo,
                                            xb, memb, Wqb, Wkb, Wvb, Wob,
                                            mask, mb16);
    gemm_qkv<<<dim3(3584), dim3(64), 0, stream>>>(xb, memb,
                                                  Wqb, bq, Qb,
                                                  Wkb, bk, Kb,
                                                  Wvb, bv, Vtb);
    attn_mfma<<<dim3(512), dim3(512), 0, stream>>>(Qb, Kb, Vtb, mb16, AOb);
    gemm_o<<<dim3(1024), dim3(64), 0, stream>>>(AOb, Wob, bo, out);
}